// Round 6
// baseline (48722.302 us; speedup 1.0000x reference)
//
#include <hip/hip_runtime.h>
#include <hip/hip_bf16.h>

#define NV 4000
#define NL 8000
#define NC 16800
#define NE 50400
#define FM 256
#define ROUNDS 32

#define F_ACC 1
#define F_RELU 2

// ---------------- utility: zero a float buffer ----------------
__global__ void zero_kernel(float* __restrict__ p, int n) {
    int i = blockIdx.x * blockDim.x + threadIdx.x;
    if (i < n) p[i] = 0.0f;
}

// ---------------- sentinel: mark loss slot so a dead loss writer is visible ----------------
__global__ void sentinel_kernel(float* __restrict__ out) {
    if (threadIdx.x == 0 && blockIdx.x == 0) out[NV] = 777.0f;
}

// ---------------- init states ----------------
__global__ void init_lh_kernel(const float* __restrict__ Li, float* __restrict__ lh) {
    int idx = blockIdx.x * blockDim.x + threadIdx.x;
    if (idx < NL * FM) lh[idx] = Li[idx & (FM - 1)] * (1.0f / 16.0f);
}
__global__ void init_ch_kernel(const float* __restrict__ Ci, float* __restrict__ ch) {
    int idx = blockIdx.x * blockDim.x + threadIdx.x;
    if (idx < NC * FM) ch[idx] = Ci[idx & (FM - 1)] * (1.0f / 16.0f);
}

// ---------------- SGEMM: C (+)= A[M,K] @ W[K,N] (ldw), + bias, relu ----------------
#define BM 64
#define BN 64
#define BK 16
__global__ __launch_bounds__(256) void sgemm_kernel(
    const float* __restrict__ A, const float* __restrict__ W,
    const float* __restrict__ bias, float* __restrict__ C,
    int M, int N, int K, int ldw, int flags)
{
    __shared__ float As[BK][BM + 1];
    __shared__ float Bs[BK][BN];
    int tid = threadIdx.x;
    int tx = tid & 15, ty = tid >> 4;
    int rowBase = blockIdx.y * BM, colBase = blockIdx.x * BN;
    float acc[4][4] = {};
    for (int k0 = 0; k0 < K; k0 += BK) {
        #pragma unroll
        for (int p = 0; p < 4; ++p) {
            int idx = p * 256 + tid;
            int r = idx >> 4, kk = idx & 15;
            int row = rowBase + r;
            As[kk][r] = (row < M) ? A[(size_t)row * K + k0 + kk] : 0.0f;
        }
        #pragma unroll
        for (int p = 0; p < 4; ++p) {
            int idx = p * 256 + tid;
            int kk = idx >> 6, col = idx & 63;
            Bs[kk][col] = W[(size_t)(k0 + kk) * ldw + colBase + col];
        }
        __syncthreads();
        #pragma unroll
        for (int kk = 0; kk < BK; ++kk) {
            float a[4], b[4];
            #pragma unroll
            for (int i = 0; i < 4; ++i) a[i] = As[kk][ty + 16 * i];
            #pragma unroll
            for (int j = 0; j < 4; ++j) b[j] = Bs[kk][tx + 16 * j];
            #pragma unroll
            for (int i = 0; i < 4; ++i)
                #pragma unroll
                for (int j = 0; j < 4; ++j)
                    acc[i][j] += a[i] * b[j];
        }
        __syncthreads();
    }
    #pragma unroll
    for (int i = 0; i < 4; ++i) {
        int row = rowBase + ty + 16 * i;
        if (row >= M) continue;
        #pragma unroll
        for (int j = 0; j < 4; ++j) {
            int col = colBase + tx + 16 * j;
            float v = acc[i][j];
            if (flags & F_ACC) v += C[(size_t)row * N + col];
            if (bias) v += bias[col];
            if (flags & F_RELU) v = fmaxf(v, 0.0f);
            C[(size_t)row * N + col] = v;
        }
    }
}

// ---------------- gather: lc_msgs[c] = sum_k lc_pre[lit(c,k)] ----------------
__global__ void gather_lc_kernel(const float* __restrict__ pre, const int* __restrict__ lits,
                                 float* __restrict__ out) {
    int idx = blockIdx.x * blockDim.x + threadIdx.x;
    if (idx >= NC * FM) return;
    int c = idx >> 8, f = idx & 255;
    const int* cl = lits + c * 3;
    float s = 0.0f;
    #pragma unroll
    for (int k = 0; k < 3; ++k) {
        int l = cl[k];
        int v = (l > 0 ? l : -l) - 1;
        int li = (l > 0) ? v : NV + v;
        s += pre[(size_t)li * FM + f];
    }
    out[idx] = s;
}

// ---------------- scatter: cl_msgs[lit(e)] += cl_pre[e/3] ----------------
__global__ void scatter_cl_kernel(const float* __restrict__ pre, const int* __restrict__ lits,
                                  float* __restrict__ out) {
    int idx = blockIdx.x * blockDim.x + threadIdx.x;
    if (idx >= NE * FM) return;
    int e = idx >> 8, f = idx & 255;
    int l = lits[e];
    int v = (l > 0 ? l : -l) - 1;
    int li = (l > 0) ? v : NV + v;
    atomicAdd(out + (size_t)li * FM + f, pre[(size_t)(e / 3) * FM + f]);
}

// ---------------- LSTM elementwise update: gates i,f,g,o from z[N,1024] ----------------
__global__ void lstm_update_kernel(const float* __restrict__ z, float* __restrict__ h,
                                   float* __restrict__ c, int n) {
    int idx = blockIdx.x * blockDim.x + threadIdx.x;
    if (idx >= n * FM) return;
    int row = idx >> 8, f = idx & 255;
    const float* zr = z + (size_t)row * 1024;
    float zi = zr[f], zf = zr[256 + f], zg = zr[512 + f], zo = zr[768 + f];
    float cold = c[idx];
    float si = 1.0f / (1.0f + expf(-zi));
    float sf = 1.0f / (1.0f + expf(-zf));
    float so = 1.0f / (1.0f + expf(-zo));
    float cn = sf * cold + si * tanhf(zg);
    float hn = so * tanhf(cn);
    c[idx] = cn;
    h[idx] = hn;
}

// ---------------- vote output GEMV: logits[v] = h1[v,:] . W2 + b2 ----------------
// Writes fp32 to ws logits AND fp32 straight into d_out (final round persists).
__global__ void vote_out_kernel(const float* __restrict__ h1, const float* __restrict__ w,
                                const float* __restrict__ b, float* __restrict__ logits_f32,
                                float* __restrict__ out_f32) {
    int gtid = blockIdx.x * blockDim.x + threadIdx.x;
    int wid = gtid >> 6;
    int lane = threadIdx.x & 63;
    if (wid >= NV) return;
    const float* hr = h1 + (size_t)wid * 512;
    float s = 0.0f;
    #pragma unroll
    for (int k = 0; k < 8; ++k) s += hr[lane + 64 * k] * w[lane + 64 * k];
    #pragma unroll
    for (int off = 32; off; off >>= 1) s += __shfl_down(s, off);
    if (lane == 0) {
        float v = s + b[0];
        logits_f32[wid] = v;
        out_f32[wid] = v;
    }
}

// ---------------- per-round clause loss: ONE block of 64 threads, no shfl/atomics ----
__global__ __launch_bounds__(64) void loss_serial_kernel(
    const float* __restrict__ logits, const int* __restrict__ lits,
    float* __restrict__ loss_arr, int r, float* __restrict__ out)
{
    __shared__ float sm[64];
    float acc = 0.0f;
    for (int c = threadIdx.x; c < NC; c += 64) {
        const int* cl = lits + c * 3;
        float s = 0.0f;
        #pragma unroll
        for (int k = 0; k < 3; ++k) {
            int l = cl[k];
            int v = (l > 0 ? l : -l) - 1;
            float sg = (l > 0) ? 1.0f : -1.0f;
            float val = logits[v] * sg;
            s += fmaxf(val, 0.0f) + log1pf(expf(-fabsf(val)));  // stable softplus
        }
        float cv = expf(-s);
        float t = -logf(1.0f - cv + 1e-8f);
        acc += t * t;
    }
    sm[threadIdx.x] = acc;
    __syncthreads();
    if (threadIdx.x == 0) {
        float s = 0.0f;
        for (int i = 0; i < 64; ++i) s += sm[i];
        loss_arr[r] = s;
        float tot = 0.0f;
        for (int q = 0; q <= r; ++q) tot += loss_arr[q];
        out[NV] = tot * (1.0f / (float)ROUNDS);
    }
}

// ---------------- final: second independent writer of out[NV] ----------------
__global__ void final_loss_kernel(const float* __restrict__ loss_arr,
                                  float* __restrict__ out) {
    if (threadIdx.x == 0 && blockIdx.x == 0) {
        float s = 0.0f;
        for (int r = 0; r < ROUNDS; ++r) s += loss_arr[r];
        out[NV] = s * (1.0f / (float)ROUNDS);
    }
}

extern "C" void kernel_launch(void* const* d_in, const int* in_sizes, int n_in,
                              void* d_out, int out_size, void* d_ws, size_t ws_size,
                              hipStream_t stream) {
    const int* lits = (const int*)d_in[0];
    float* out = (float*)d_out;   // reference output dtype is float32

    // ---- float32 inputs, in setup_inputs() dict order (d_in[1] is n_vars scalar) ----
    const float* Li   = (const float*)d_in[2];
    const float* Ci   = (const float*)d_in[3];
    const float* LCW0 = (const float*)d_in[4];
    const float* LCb0 = (const float*)d_in[5];
    const float* LCW1 = (const float*)d_in[6];
    const float* LCb1 = (const float*)d_in[7];
    const float* LCW2 = (const float*)d_in[8];
    const float* LCb2 = (const float*)d_in[9];
    const float* CLW0 = (const float*)d_in[10];
    const float* CLb0 = (const float*)d_in[11];
    const float* CLW1 = (const float*)d_in[12];
    const float* CLb1 = (const float*)d_in[13];
    const float* CLW2 = (const float*)d_in[14];
    const float* CLb2 = (const float*)d_in[15];
    const float* CWx  = (const float*)d_in[16];
    const float* CWh  = (const float*)d_in[17];
    const float* Cb   = (const float*)d_in[18];
    const float* LWx  = (const float*)d_in[19];
    const float* LWh  = (const float*)d_in[20];
    const float* Lb   = (const float*)d_in[21];
    const float* VW0  = (const float*)d_in[22];
    const float* Vb0  = (const float*)d_in[23];
    const float* VW1  = (const float*)d_in[24];
    const float* Vb1  = (const float*)d_in[25];
    const float* VW2  = (const float*)d_in[26];
    const float* Vb2  = (const float*)d_in[27];

    // ---- ws layout (floats): small/critical buffers first ----
    float* base = (float*)d_ws;
    size_t off = 0;
    auto alloc = [&](size_t n) { float* p = base + off; off += n; return p; };

    float* loss_arr = alloc(ROUNDS);            // @0
    float* logits   = alloc(NV);
    float* lh   = alloc((size_t)NL * FM);
    float* lc   = alloc((size_t)NL * FM);
    float* ch   = alloc((size_t)NC * FM);
    float* cc   = alloc((size_t)NC * FM);
    float* bufA = alloc((size_t)NC * FM);
    float* bufB = alloc((size_t)NC * FM);
    float* bufC = alloc((size_t)NC * FM);
    float* zbuf = alloc((size_t)NC * 1024);
    (void)ws_size; (void)in_sizes; (void)n_in; (void)out_size;

    // ---- sentinel + init states ----
    hipLaunchKernelGGL(sentinel_kernel, dim3(1), dim3(64), 0, stream, out);
    hipLaunchKernelGGL(init_lh_kernel, dim3(NL * FM / 256), dim3(256), 0, stream, Li, lh);
    hipLaunchKernelGGL(init_ch_kernel, dim3(NC * FM / 256), dim3(256), 0, stream, Ci, ch);
    hipLaunchKernelGGL(zero_kernel, dim3(NL * FM / 256), dim3(256), 0, stream, lc, NL * FM);
    hipLaunchKernelGGL(zero_kernel, dim3(NC * FM / 256), dim3(256), 0, stream, cc, NC * FM);

    auto gemm = [&](const float* A, const float* W, const float* b, float* C,
                    int M, int N, int K, int ldw, int flags) {
        dim3 g(N / BN, (M + BM - 1) / BM);
        hipLaunchKernelGGL(sgemm_kernel, g, dim3(256), 0, stream, A, W, b, C, M, N, K, ldw, flags);
    };

    for (int r = 0; r < ROUNDS; ++r) {
        // L -> C message MLP (lc_pre in bufA)
        gemm(lh,   LCW0, LCb0, bufA, NL, 256, 256, 256, F_RELU);
        gemm(bufA, LCW1, LCb1, bufB, NL, 256, 256, 256, F_RELU);
        gemm(bufB, LCW2, LCb2, bufA, NL, 256, 256, 256, 0);
        // gather into clauses (bufC = lc_msgs [NC,256])
        hipLaunchKernelGGL(gather_lc_kernel, dim3(NC * FM / 256), dim3(256), 0, stream,
                           bufA, lits, bufC);
        // clause LSTM: z = lc_msgs@C_Wx + ch@C_Wh + b
        gemm(bufC, CWx, Cb,   zbuf, NC, 1024, 256, 1024, 0);
        gemm(ch,   CWh, NULL, zbuf, NC, 1024, 256, 1024, F_ACC);
        hipLaunchKernelGGL(lstm_update_kernel, dim3((NC * FM + 255) / 256), dim3(256), 0, stream,
                           zbuf, ch, cc, NC);
        // C -> L message MLP (cl_pre in bufA)
        gemm(ch,   CLW0, CLb0, bufA, NC, 256, 256, 256, F_RELU);
        gemm(bufA, CLW1, CLb1, bufB, NC, 256, 256, 256, F_RELU);
        gemm(bufB, CLW2, CLb2, bufA, NC, 256, 256, 256, 0);
        // scatter into literals (bufC = cl_msgs [NL,256])
        hipLaunchKernelGGL(zero_kernel, dim3(NL * FM / 256), dim3(256), 0, stream, bufC, NL * FM);
        hipLaunchKernelGGL(scatter_cl_kernel, dim3(NE * FM / 256), dim3(256), 0, stream,
                           bufA, lits, bufC);
        // literal LSTM: z = [cl_msgs, flipped]@L_Wx + lh@L_Wh + b
        gemm(bufC, LWx, Lb, zbuf, NL, 1024, 256, 1024, 0);
        gemm(lh + (size_t)NV * FM, LWx + 256 * 1024, NULL, zbuf,                     NV, 1024, 256, 1024, F_ACC);
        gemm(lh,                   LWx + 256 * 1024, NULL, zbuf + (size_t)NV * 1024, NV, 1024, 256, 1024, F_ACC);
        gemm(lh, LWh, NULL, zbuf, NL, 1024, 256, 1024, F_ACC);
        hipLaunchKernelGGL(lstm_update_kernel, dim3((NL * FM + 255) / 256), dim3(256), 0, stream,
                           zbuf, lh, lc, NL);
        // vote MLP: variables = [lh_pos, lh_neg] (feature concat)
        gemm(lh,                   VW0,             Vb0,  bufA, NV, 512, 256, 512, 0);
        gemm(lh + (size_t)NV * FM, VW0 + 256 * 512, NULL, bufA, NV, 512, 256, 512, F_ACC | F_RELU);
        gemm(bufA, VW1, Vb1, bufB, NV, 512, 512, 512, F_RELU);
        hipLaunchKernelGGL(vote_out_kernel, dim3(NV * 64 / 256), dim3(256), 0, stream,
                           bufB, VW2, Vb2, logits, out);
        // per-round clause loss: writes loss_arr[r] AND out[NV] (fp32)
        hipLaunchKernelGGL(loss_serial_kernel, dim3(1), dim3(64), 0, stream,
                           logits, lits, loss_arr, r, out);
    }

    // second independent writer of out[NV]
    hipLaunchKernelGGL(final_loss_kernel, dim3(1), dim3(64), 0, stream, loss_arr, out);
}

// Round 7
// 19439.119 us; speedup vs baseline: 2.5064x; 2.5064x over previous
//
#include <hip/hip_runtime.h>
#include <hip/hip_bf16.h>

#define NV 4000
#define NL 8000
#define NC 16800
#define NE 50400
#define FM 256
#define ROUNDS 32

typedef short s16x8 __attribute__((ext_vector_type(8)));
typedef __bf16 b16x8 __attribute__((ext_vector_type(8)));
typedef float f32x4 __attribute__((ext_vector_type(4)));
union V8 { s16x8 s; b16x8 b; };

__device__ __forceinline__ float b2f(ushort u) {
    union { uint i; float f; } v; v.i = ((uint)u) << 16; return v.f;
}
__device__ __forceinline__ ushort f2b(float f) {
    __hip_bfloat16 h = __float2bfloat16(f);
    return *(ushort*)&h;
}

// ---------------- utility ----------------
__global__ void zero_kernel(float* __restrict__ p, int n) {
    int i = blockIdx.x * blockDim.x + threadIdx.x;
    if (i < n) p[i] = 0.0f;
}
__global__ void f2b_kernel(const float* __restrict__ src, ushort* __restrict__ dst, int n) {
    int i = blockIdx.x * blockDim.x + threadIdx.x;
    if (i < n) dst[i] = f2b(src[i]);
}
// W [K,N] fp32 -> out [N, ldo] bf16 at column offset koff (B^T layout)
__global__ void transpose_w_kernel(const float* __restrict__ in, ushort* __restrict__ out,
                                   int K, int N, int ldo, int koff) {
    int idx = blockIdx.x * blockDim.x + threadIdx.x;
    if (idx >= K * N) return;
    int n = idx / K, k = idx - n * K;
    out[(size_t)n * ldo + koff + k] = f2b(in[(size_t)k * N + n]);
}

// ---------------- init states ----------------
__global__ void init_lh_kernel(const float* __restrict__ Li, ushort* __restrict__ lh,
                               ushort* __restrict__ lhflip) {
    int idx = blockIdx.x * blockDim.x + threadIdx.x;
    if (idx < NL * FM) {
        ushort v = f2b(Li[idx & (FM - 1)] * (1.0f / 16.0f));
        lh[idx] = v; lhflip[idx] = v;
    }
}
__global__ void init_ch_kernel(const float* __restrict__ Ci, ushort* __restrict__ ch) {
    int idx = blockIdx.x * blockDim.x + threadIdx.x;
    if (idx < NC * FM) ch[idx] = f2b(Ci[idx & (FM - 1)] * (1.0f / 16.0f));
}

// ---------------- MFMA bf16 GEMM: C16[M,N] = concat_A @ Bt^T + bias (relu opt) ------
// A given as up to 3 row-major bf16 slices [M, Ki] (ld = Ki); Bt is [N, Ktot] bf16.
#define TM 128
#define TN 128
#define TBK 32
#define LDP 56
__global__ __launch_bounds__(256) void gemm16_kernel(
    const ushort* __restrict__ A0, int K0,
    const ushort* __restrict__ A1, int K1,
    const ushort* __restrict__ A2, int K2,
    const ushort* __restrict__ Bt, const float* __restrict__ bias,
    ushort* __restrict__ C, int M, int N, int relu)
{
    __shared__ __align__(16) short Al[TM * LDP];
    __shared__ __align__(16) short Bl[TN * LDP];
    const int Ktot = K0 + K1 + K2;
    const int tid = threadIdx.x;
    const int rowBase = blockIdx.y * TM, colBase = blockIdx.x * TN;
    const int lane = tid & 63, wid = tid >> 6;
    const int wm = (wid >> 1) * 64, wn = (wid & 1) * 64;
    f32x4 acc[4][4];
    #pragma unroll
    for (int i = 0; i < 4; ++i)
        #pragma unroll
        for (int j = 0; j < 4; ++j)
            acc[i][j] = (f32x4){0.f, 0.f, 0.f, 0.f};

    for (int k0 = 0; k0 < Ktot; k0 += TBK) {
        const ushort* As; int ks, lda;
        if (k0 < K0)            { As = A0; ks = k0;            lda = K0; }
        else if (k0 < K0 + K1)  { As = A1; ks = k0 - K0;       lda = K1; }
        else                    { As = A2; ks = k0 - K0 - K1;  lda = K2; }
        __syncthreads();
        #pragma unroll
        for (int p = 0; p < 2; ++p) {
            int idx = p * 256 + tid;
            int r = idx >> 2, cg = (idx & 3) * 8;
            uint4 va = make_uint4(0u, 0u, 0u, 0u);
            int grow = rowBase + r;
            if (grow < M) va = *(const uint4*)(As + (size_t)grow * lda + ks + cg);
            *(uint4*)&Al[r * LDP + cg] = va;
            uint4 vb = *(const uint4*)(Bt + (size_t)(colBase + r) * Ktot + k0 + cg);
            *(uint4*)&Bl[r * LDP + cg] = vb;
        }
        __syncthreads();
        const int kq = (lane >> 4) * 8, cl = lane & 15;
        V8 af[4], bf[4];
        #pragma unroll
        for (int i = 0; i < 4; ++i) af[i].s = *(const s16x8*)&Al[(wm + i * 16 + cl) * LDP + kq];
        #pragma unroll
        for (int j = 0; j < 4; ++j) bf[j].s = *(const s16x8*)&Bl[(wn + j * 16 + cl) * LDP + kq];
        #pragma unroll
        for (int i = 0; i < 4; ++i)
            #pragma unroll
            for (int j = 0; j < 4; ++j)
                acc[i][j] = __builtin_amdgcn_mfma_f32_16x16x32_bf16(af[i].b, bf[j].b, acc[i][j], 0, 0, 0);
    }
    // epilogue: C row = (lane>>4)*4 + reg, col = lane&15  [m89-verified layout]
    const int rq = (lane >> 4) * 4, cl = lane & 15;
    #pragma unroll
    for (int i = 0; i < 4; ++i) {
        #pragma unroll
        for (int r = 0; r < 4; ++r) {
            int grow = rowBase + wm + i * 16 + rq + r;
            if (grow >= M) continue;
            #pragma unroll
            for (int j = 0; j < 4; ++j) {
                int gcol = colBase + wn + j * 16 + cl;
                float v = acc[i][j][r];
                if (bias) v += bias[gcol];
                if (relu) v = fmaxf(v, 0.0f);
                C[(size_t)grow * N + gcol] = f2b(v);
            }
        }
    }
}

// ---------------- gather: lcm[c] = sum_k lc_pre[lit(c,k)]  (bf16 in/out) ------------
__global__ void gather_lc_kernel(const ushort* __restrict__ pre, const int* __restrict__ lits,
                                 ushort* __restrict__ out) {
    int idx = blockIdx.x * blockDim.x + threadIdx.x;
    if (idx >= NC * FM) return;
    int c = idx >> 8, f = idx & 255;
    const int* cl = lits + c * 3;
    float s = 0.0f;
    #pragma unroll
    for (int k = 0; k < 3; ++k) {
        int l = cl[k];
        int v = (l > 0 ? l : -l) - 1;
        int li = (l > 0) ? v : NV + v;
        s += b2f(pre[(size_t)li * FM + f]);
    }
    out[idx] = f2b(s);
}

// ---------------- scatter: clm32[lit(e)] += cl_pre[e/3]  (bf16 -> fp32 atomics) ------
__global__ void scatter_cl_kernel(const ushort* __restrict__ pre, const int* __restrict__ lits,
                                  float* __restrict__ out) {
    int idx = blockIdx.x * blockDim.x + threadIdx.x;
    if (idx >= NE * FM) return;
    int e = idx >> 8, f = idx & 255;
    int l = lits[e];
    int v = (l > 0 ? l : -l) - 1;
    int li = (l > 0) ? v : NV + v;
    atomicAdd(out + (size_t)li * FM + f, b2f(pre[(size_t)(e / 3) * FM + f]));
}

// ---------------- LSTM elementwise: z bf16 [n,1024] gates i,f,g,o -------------------
__global__ void lstm_update_kernel(const ushort* __restrict__ z, ushort* __restrict__ h,
                                   ushort* __restrict__ hflip, float* __restrict__ c, int n) {
    int idx = blockIdx.x * blockDim.x + threadIdx.x;
    if (idx >= n * FM) return;
    int row = idx >> 8, f = idx & 255;
    const ushort* zr = z + (size_t)row * 1024;
    float zi = b2f(zr[f]), zf = b2f(zr[256 + f]), zg = b2f(zr[512 + f]), zo = b2f(zr[768 + f]);
    float cold = c[idx];
    float si = 1.0f / (1.0f + __expf(-zi));
    float sf = 1.0f / (1.0f + __expf(-zf));
    float so = 1.0f / (1.0f + __expf(-zo));
    float cn = sf * cold + si * tanhf(zg);
    float hn = so * tanhf(cn);
    c[idx] = cn;
    ushort hb = f2b(hn);
    h[idx] = hb;
    if (hflip) hflip[(size_t)((row + NV) % NL) * FM + f] = hb;
}

// ---------------- vote output GEMV (bf16 inputs) ------------------------------------
__global__ void vote_out_kernel(const ushort* __restrict__ h1, const ushort* __restrict__ w,
                                const float* __restrict__ b, float* __restrict__ logits_f32,
                                float* __restrict__ out_f32) {
    int gtid = blockIdx.x * blockDim.x + threadIdx.x;
    int wid = gtid >> 6;
    int lane = threadIdx.x & 63;
    if (wid >= NV) return;
    const ushort* hr = h1 + (size_t)wid * 512;
    float s = 0.0f;
    #pragma unroll
    for (int k = 0; k < 8; ++k) s += b2f(hr[lane + 64 * k]) * b2f(w[lane + 64 * k]);
    #pragma unroll
    for (int off = 32; off; off >>= 1) s += __shfl_down(s, off);
    if (lane == 0) {
        float v = s + b[0];
        logits_f32[wid] = v;
        out_f32[wid] = v;
    }
}

// ---------------- per-round clause loss ---------------------------------------------
__global__ __launch_bounds__(64) void loss_serial_kernel(
    const float* __restrict__ logits, const int* __restrict__ lits,
    float* __restrict__ loss_arr, int r)
{
    __shared__ float sm[64];
    float acc = 0.0f;
    for (int c = threadIdx.x; c < NC; c += 64) {
        const int* cl = lits + c * 3;
        float s = 0.0f;
        #pragma unroll
        for (int k = 0; k < 3; ++k) {
            int l = cl[k];
            int v = (l > 0 ? l : -l) - 1;
            float sg = (l > 0) ? 1.0f : -1.0f;
            float val = logits[v] * sg;
            s += fmaxf(val, 0.0f) + log1pf(expf(-fabsf(val)));
        }
        float cv = expf(-s);
        float t = -logf(1.0f - cv + 1e-8f);
        acc += t * t;
    }
    sm[threadIdx.x] = acc;
    __syncthreads();
    if (threadIdx.x == 0) {
        float s = 0.0f;
        for (int i = 0; i < 64; ++i) s += sm[i];
        loss_arr[r] = s;
    }
}

__global__ void final_loss_kernel(const float* __restrict__ loss_arr, float* __restrict__ out) {
    if (threadIdx.x == 0 && blockIdx.x == 0) {
        float s = 0.0f;
        for (int r = 0; r < ROUNDS; ++r) s += loss_arr[r];
        out[NV] = s * (1.0f / (float)ROUNDS);
    }
}

extern "C" void kernel_launch(void* const* d_in, const int* in_sizes, int n_in,
                              void* d_out, int out_size, void* d_ws, size_t ws_size,
                              hipStream_t stream) {
    const int* lits = (const int*)d_in[0];
    float* out = (float*)d_out;   // fp32 output: 4000 logits + loss

    const float* Li   = (const float*)d_in[2];
    const float* Ci   = (const float*)d_in[3];
    const float* LCW0 = (const float*)d_in[4];
    const float* LCb0 = (const float*)d_in[5];
    const float* LCW1 = (const float*)d_in[6];
    const float* LCb1 = (const float*)d_in[7];
    const float* LCW2 = (const float*)d_in[8];
    const float* LCb2 = (const float*)d_in[9];
    const float* CLW0 = (const float*)d_in[10];
    const float* CLb0 = (const float*)d_in[11];
    const float* CLW1 = (const float*)d_in[12];
    const float* CLb1 = (const float*)d_in[13];
    const float* CLW2 = (const float*)d_in[14];
    const float* CLb2 = (const float*)d_in[15];
    const float* CWx  = (const float*)d_in[16];
    const float* CWh  = (const float*)d_in[17];
    const float* Cb   = (const float*)d_in[18];
    const float* LWx  = (const float*)d_in[19];
    const float* LWh  = (const float*)d_in[20];
    const float* Lb   = (const float*)d_in[21];
    const float* VW0  = (const float*)d_in[22];
    const float* Vb0  = (const float*)d_in[23];
    const float* VW1  = (const float*)d_in[24];
    const float* Vb1  = (const float*)d_in[25];
    const float* VW2  = (const float*)d_in[26];
    const float* Vb2  = (const float*)d_in[27];
    (void)in_sizes; (void)n_in; (void)out_size; (void)ws_size;

    // ---- ws layout ----
    char* base = (char*)d_ws;
    size_t off = 0;
    auto allocB = [&](size_t bytes) {
        void* p = base + off;
        off += (bytes + 15) & ~(size_t)15;
        return p;
    };
    float*  loss_arr = (float*)allocB(ROUNDS * 4);
    float*  logits   = (float*)allocB(NV * 4);
    float*  lc32     = (float*)allocB((size_t)NL * FM * 4);
    float*  cc32     = (float*)allocB((size_t)NC * FM * 4);
    float*  clm32    = (float*)allocB((size_t)NL * FM * 4);
    // bf16 weights (B^T layouts)
    ushort* LC0t = (ushort*)allocB((size_t)256 * 256 * 2);
    ushort* LC1t = (ushort*)allocB((size_t)256 * 256 * 2);
    ushort* LC2t = (ushort*)allocB((size_t)256 * 256 * 2);
    ushort* CL0t = (ushort*)allocB((size_t)256 * 256 * 2);
    ushort* CL1t = (ushort*)allocB((size_t)256 * 256 * 2);
    ushort* CL2t = (ushort*)allocB((size_t)256 * 256 * 2);
    ushort* CWt  = (ushort*)allocB((size_t)1024 * 512 * 2);   // [1024, 512] = [CWx^T | CWh^T]
    ushort* LWt  = (ushort*)allocB((size_t)1024 * 768 * 2);   // [1024, 768] = [LWx^T | LWh^T]
    ushort* VW0t = (ushort*)allocB((size_t)512 * 512 * 2);
    ushort* VW1t = (ushort*)allocB((size_t)512 * 512 * 2);
    ushort* vw2  = (ushort*)allocB((size_t)512 * 2);
    // bf16 activations
    ushort* lh16     = (ushort*)allocB((size_t)NL * FM * 2);
    ushort* lhflip16 = (ushort*)allocB((size_t)NL * FM * 2);
    ushort* ch16     = (ushort*)allocB((size_t)NC * FM * 2);
    ushort* lcm16    = (ushort*)allocB((size_t)NC * FM * 2);
    ushort* t0       = (ushort*)allocB((size_t)NC * FM * 2);
    ushort* t1       = (ushort*)allocB((size_t)NC * FM * 2);
    ushort* t2       = (ushort*)allocB((size_t)NC * FM * 2);
    ushort* clm16    = (ushort*)allocB((size_t)NL * FM * 2);
    ushort* v0       = (ushort*)allocB((size_t)NV * 512 * 2);
    ushort* v1       = (ushort*)allocB((size_t)NV * 512 * 2);
    ushort* zC16     = (ushort*)allocB((size_t)NC * 1024 * 2);
    ushort* zL16     = (ushort*)allocB((size_t)NL * 1024 * 2);

    // ---- one-time per launch: weight convert/transpose + state init ----
    auto tw = [&](const float* in, ushort* o, int K, int N, int ldo, int koff) {
        hipLaunchKernelGGL(transpose_w_kernel, dim3((K * N + 255) / 256), dim3(256), 0, stream,
                           in, o, K, N, ldo, koff);
    };
    tw(LCW0, LC0t, 256, 256, 256, 0);
    tw(LCW1, LC1t, 256, 256, 256, 0);
    tw(LCW2, LC2t, 256, 256, 256, 0);
    tw(CLW0, CL0t, 256, 256, 256, 0);
    tw(CLW1, CL1t, 256, 256, 256, 0);
    tw(CLW2, CL2t, 256, 256, 256, 0);
    tw(CWx,  CWt, 256, 1024, 512, 0);
    tw(CWh,  CWt, 256, 1024, 512, 256);
    tw(LWx,  LWt, 512, 1024, 768, 0);
    tw(LWh,  LWt, 256, 1024, 768, 512);
    tw(VW0,  VW0t, 512, 512, 512, 0);
    tw(VW1,  VW1t, 512, 512, 512, 0);
    hipLaunchKernelGGL(f2b_kernel, dim3(2), dim3(256), 0, stream, VW2, vw2, 512);

    hipLaunchKernelGGL(init_lh_kernel, dim3(NL * FM / 256), dim3(256), 0, stream, Li, lh16, lhflip16);
    hipLaunchKernelGGL(init_ch_kernel, dim3(NC * FM / 256), dim3(256), 0, stream, Ci, ch16);
    hipLaunchKernelGGL(zero_kernel, dim3(NL * FM / 256), dim3(256), 0, stream, lc32, NL * FM);
    hipLaunchKernelGGL(zero_kernel, dim3(NC * FM / 256), dim3(256), 0, stream, cc32, NC * FM);

    auto gemm = [&](const ushort* A0, int K0, const ushort* A1, int K1,
                    const ushort* A2, int K2, const ushort* Bt, const float* bias,
                    ushort* C, int M, int N, int relu) {
        dim3 g(N / TN, (M + TM - 1) / TM);
        hipLaunchKernelGGL(gemm16_kernel, g, dim3(256), 0, stream,
                           A0, K0, A1, K1, A2, K2, Bt, bias, C, M, N, relu);
    };

    for (int r = 0; r < ROUNDS; ++r) {
        // L -> C message MLP
        gemm(lh16, 256, 0, 0, 0, 0, LC0t, LCb0, t0, NL, 256, 1);
        gemm(t0,   256, 0, 0, 0, 0, LC1t, LCb1, t1, NL, 256, 1);
        gemm(t1,   256, 0, 0, 0, 0, LC2t, LCb2, t2, NL, 256, 0);
        // gather into clauses
        hipLaunchKernelGGL(gather_lc_kernel, dim3(NC * FM / 256), dim3(256), 0, stream,
                           t2, lits, lcm16);
        // clause LSTM: z = [lcm, ch] @ CWt^T + Cb
        gemm(lcm16, 256, ch16, 256, 0, 0, CWt, Cb, zC16, NC, 1024, 0);
        hipLaunchKernelGGL(lstm_update_kernel, dim3(NC * FM / 256), dim3(256), 0, stream,
                           zC16, ch16, (ushort*)0, cc32, NC);
        // C -> L message MLP
        gemm(ch16, 256, 0, 0, 0, 0, CL0t, CLb0, t0, NC, 256, 1);
        gemm(t0,   256, 0, 0, 0, 0, CL1t, CLb1, t1, NC, 256, 1);
        gemm(t1,   256, 0, 0, 0, 0, CL2t, CLb2, t2, NC, 256, 0);
        // scatter into literals
        hipLaunchKernelGGL(zero_kernel, dim3(NL * FM / 256), dim3(256), 0, stream, clm32, NL * FM);
        hipLaunchKernelGGL(scatter_cl_kernel, dim3(NE * FM / 256), dim3(256), 0, stream,
                           t2, lits, clm32);
        hipLaunchKernelGGL(f2b_kernel, dim3(NL * FM / 256), dim3(256), 0, stream,
                           clm32, clm16, NL * FM);
        // literal LSTM: z = [clm, flipped, lh] @ LWt^T + Lb
        gemm(clm16, 256, lhflip16, 256, lh16, 256, LWt, Lb, zL16, NL, 1024, 0);
        hipLaunchKernelGGL(lstm_update_kernel, dim3(NL * FM / 256), dim3(256), 0, stream,
                           zL16, lh16, lhflip16, lc32, NL);
        // vote MLP
        gemm(lh16, 256, lh16 + (size_t)NV * FM, 256, 0, 0, VW0t, Vb0, v0, NV, 512, 1);
        gemm(v0, 512, 0, 0, 0, 0, VW1t, Vb1, v1, NV, 512, 1);
        hipLaunchKernelGGL(vote_out_kernel, dim3(NV * 64 / 256), dim3(256), 0, stream,
                           v1, vw2, Vb2, logits, out);
        hipLaunchKernelGGL(loss_serial_kernel, dim3(1), dim3(64), 0, stream,
                           logits, lits, loss_arr, r);
    }

    hipLaunchKernelGGL(final_loss_kernel, dim3(1), dim3(64), 0, stream, loss_arr, out);
}

// Round 8
// 9874.675 us; speedup vs baseline: 4.9341x; 1.9686x over previous
//
#include <hip/hip_runtime.h>
#include <hip/hip_bf16.h>

#define NV 4000
#define NL 8000
#define NC 16800
#define NE 50400
#define FM 256
#define ROUNDS 32

typedef short s16x8 __attribute__((ext_vector_type(8)));
typedef __bf16 b16x8 __attribute__((ext_vector_type(8)));
typedef float f32x4 __attribute__((ext_vector_type(4)));
union V8 { s16x8 s; b16x8 b; };

using gaddr_t = const void __attribute__((address_space(1)))*;
using laddr_t = void __attribute__((address_space(3)))*;

__device__ __forceinline__ float b2f(ushort u) {
    union { uint i; float f; } v; v.i = ((uint)u) << 16; return v.f;
}
__device__ __forceinline__ ushort f2b(float f) {
    __hip_bfloat16 h = __float2bfloat16(f);
    return *(ushort*)&h;
}

// ---------------- utility ----------------
__global__ void zero_kernel(float* __restrict__ p, int n) {
    int i = blockIdx.x * blockDim.x + threadIdx.x;
    if (i < n) p[i] = 0.0f;
}
__global__ void f2b_kernel(const float* __restrict__ src, ushort* __restrict__ dst, int n) {
    int i = blockIdx.x * blockDim.x + threadIdx.x;
    if (i < n) dst[i] = f2b(src[i]);
}
// W [K,N] fp32 -> out [N, ldo] bf16 at column offset koff (B^T layout)
__global__ void transpose_w_kernel(const float* __restrict__ in, ushort* __restrict__ out,
                                   int K, int N, int ldo, int koff) {
    int idx = blockIdx.x * blockDim.x + threadIdx.x;
    if (idx >= K * N) return;
    int n = idx / K, k = idx - n * K;
    out[(size_t)n * ldo + koff + k] = f2b(in[(size_t)k * N + n]);
}

// ---------------- init states ----------------
__global__ void init_lh_kernel(const float* __restrict__ Li, ushort* __restrict__ lh,
                               ushort* __restrict__ lhflip) {
    int idx = blockIdx.x * blockDim.x + threadIdx.x;
    if (idx < NL * FM) {
        ushort v = f2b(Li[idx & (FM - 1)] * (1.0f / 16.0f));
        lh[idx] = v; lhflip[idx] = v;
    }
}
__global__ void init_ch_kernel(const float* __restrict__ Ci, ushort* __restrict__ ch) {
    int idx = blockIdx.x * blockDim.x + threadIdx.x;
    if (idx < NC * FM) ch[idx] = f2b(Ci[idx & (FM - 1)] * (1.0f / 16.0f));
}

// ---------------- CSR build for scatter->gather ----------------
__global__ void csr_count_kernel(const int* __restrict__ lits, int* __restrict__ deg) {
    int e = blockIdx.x * blockDim.x + threadIdx.x;
    if (e >= NE) return;
    int l = lits[e];
    int v = (l > 0 ? l : -l) - 1;
    int li = (l > 0) ? v : NV + v;
    atomicAdd(&deg[li], 1);
}
__global__ void csr_scan_kernel(const int* __restrict__ deg, int* __restrict__ rowptr,
                                int* __restrict__ nxt) {
    if (threadIdx.x == 0 && blockIdx.x == 0) {
        int acc = 0;
        for (int i = 0; i < NL; ++i) { rowptr[i] = acc; nxt[i] = acc; acc += deg[i]; }
        rowptr[NL] = acc;
    }
}
__global__ void csr_fill_kernel(const int* __restrict__ lits, int* __restrict__ nxt,
                                int* __restrict__ ecl) {
    int e = blockIdx.x * blockDim.x + threadIdx.x;
    if (e >= NE) return;
    int l = lits[e];
    int v = (l > 0 ? l : -l) - 1;
    int li = (l > 0) ? v : NV + v;
    int pos = atomicAdd(&nxt[li], 1);
    ecl[pos] = e / 3;
}

// ---------------- MFMA bf16 GEMM, global_load_lds staging, XOR-8 swizzle ------------
// C16[M,N] = concat(A0,A1,A2) @ Bt^T + bias (relu opt). A slices row-major [M,Ki],
// Ki multiple of 64; Bt is [N,Ktot]; N multiple of 128.
#define TM 128
#define TN 128
#define BKT 64
__global__ __launch_bounds__(256) void gemm16_kernel(
    const ushort* __restrict__ A0, int K0,
    const ushort* __restrict__ A1, int K1,
    const ushort* __restrict__ A2, int K2,
    const ushort* __restrict__ Bt, const float* __restrict__ bias,
    ushort* __restrict__ C, int M, int N, int relu)
{
    __shared__ __align__(16) ushort Al[TM * BKT];
    __shared__ __align__(16) ushort Bl[TN * BKT];
    const int Ktot = K0 + K1 + K2;
    const int tid = threadIdx.x;
    const int rowBase = blockIdx.y * TM, colBase = blockIdx.x * TN;
    const int lane = tid & 63, wid = tid >> 6;
    const int wm = (wid >> 1) * 64, wn = (wid & 1) * 64;
    // staging lane roles: 8 rows x 8 chunks(16B) per instruction
    const int lr = lane >> 3;            // row within 8-row group (= row&7)
    const int ql = (lane & 7) ^ lr;      // logical k-chunk this lane fetches (XOR swizzle)

    f32x4 acc[4][4];
    #pragma unroll
    for (int i = 0; i < 4; ++i)
        #pragma unroll
        for (int j = 0; j < 4; ++j)
            acc[i][j] = (f32x4){0.f, 0.f, 0.f, 0.f};

    for (int k0 = 0; k0 < Ktot; k0 += BKT) {
        const ushort* As; int ks, lda;
        if (k0 < K0)           { As = A0; ks = k0;           lda = K0; }
        else if (k0 < K0 + K1) { As = A1; ks = k0 - K0;      lda = K1; }
        else                   { As = A2; ks = k0 - K0 - K1; lda = K2; }
        __syncthreads();   // previous iter's LDS reads complete before overwrite
        #pragma unroll
        for (int t = 0; t < 4; ++t) {
            int rloc = (wid * 4 + t) * 8 + lr;
            int ga = rowBase + rloc; if (ga > M - 1) ga = M - 1;
            const ushort* gp = As + (size_t)ga * lda + ks + ql * 8;
            __builtin_amdgcn_global_load_lds((gaddr_t)gp, (laddr_t)&Al[(wid * 4 + t) * 512],
                                             16, 0, 0);
            const ushort* gpb = Bt + (size_t)(colBase + rloc) * Ktot + k0 + ql * 8;
            __builtin_amdgcn_global_load_lds((gaddr_t)gpb, (laddr_t)&Bl[(wid * 4 + t) * 512],
                                             16, 0, 0);
        }
        __syncthreads();   // drains vmcnt (global_load_lds) before reads
        const int cl = lane & 15, kg = lane >> 4;
        #pragma unroll
        for (int s = 0; s < 2; ++s) {
            V8 af[4], bf[4];
            #pragma unroll
            for (int i = 0; i < 4; ++i) {
                int m = wm + i * 16 + cl;
                int q = (s * 4 + kg) ^ (m & 7);
                af[i].s = *(const s16x8*)&Al[m * BKT + q * 8];
            }
            #pragma unroll
            for (int j = 0; j < 4; ++j) {
                int n = wn + j * 16 + cl;
                int q = (s * 4 + kg) ^ (n & 7);
                bf[j].s = *(const s16x8*)&Bl[n * BKT + q * 8];
            }
            #pragma unroll
            for (int i = 0; i < 4; ++i)
                #pragma unroll
                for (int j = 0; j < 4; ++j)
                    acc[i][j] = __builtin_amdgcn_mfma_f32_16x16x32_bf16(af[i].b, bf[j].b,
                                                                        acc[i][j], 0, 0, 0);
        }
    }
    // epilogue: C row = (lane>>4)*4 + reg, col = lane&15
    const int rq = (lane >> 4) * 4, cl = lane & 15;
    #pragma unroll
    for (int i = 0; i < 4; ++i) {
        #pragma unroll
        for (int r = 0; r < 4; ++r) {
            int grow = rowBase + wm + i * 16 + rq + r;
            if (grow >= M) continue;
            #pragma unroll
            for (int j = 0; j < 4; ++j) {
                int gcol = colBase + wn + j * 16 + cl;
                float v = acc[i][j][r];
                if (bias) v += bias[gcol];
                if (relu) v = fmaxf(v, 0.0f);
                C[(size_t)grow * N + gcol] = f2b(v);
            }
        }
    }
}

// ---------------- gather: lcm[c] = sum_k lc_pre[lit(c,k)]  (bf16 in/out) ------------
__global__ void gather_lc_kernel(const ushort* __restrict__ pre, const int* __restrict__ lits,
                                 ushort* __restrict__ out) {
    int idx = blockIdx.x * blockDim.x + threadIdx.x;
    if (idx >= NC * FM) return;
    int c = idx >> 8, f = idx & 255;
    const int* cl = lits + c * 3;
    float s = 0.0f;
    #pragma unroll
    for (int k = 0; k < 3; ++k) {
        int l = cl[k];
        int v = (l > 0 ? l : -l) - 1;
        int li = (l > 0) ? v : NV + v;
        s += b2f(pre[(size_t)li * FM + f]);
    }
    out[idx] = f2b(s);
}

// ---------------- CSR gather: clm[li] = sum_{e in lit li} cl_pre[clause(e)] ----------
__global__ void gather_cl_kernel(const ushort* __restrict__ pre, const int* __restrict__ rowptr,
                                 const int* __restrict__ ecl, ushort* __restrict__ out) {
    int idx = blockIdx.x * blockDim.x + threadIdx.x;
    if (idx >= NL * FM) return;
    int li = idx >> 8, f = idx & 255;
    int j0 = rowptr[li], j1 = rowptr[li + 1];
    float s = 0.0f;
    for (int j = j0; j < j1; ++j) s += b2f(pre[(size_t)ecl[j] * FM + f]);
    out[idx] = f2b(s);
}

// ---------------- LSTM elementwise: z bf16 [n,1024] gates i,f,g,o -------------------
__global__ void lstm_update_kernel(const ushort* __restrict__ z, ushort* __restrict__ h,
                                   ushort* __restrict__ hflip, float* __restrict__ c, int n) {
    int idx = blockIdx.x * blockDim.x + threadIdx.x;
    if (idx >= n * FM) return;
    int row = idx >> 8, f = idx & 255;
    const ushort* zr = z + (size_t)row * 1024;
    float zi = b2f(zr[f]), zf = b2f(zr[256 + f]), zg = b2f(zr[512 + f]), zo = b2f(zr[768 + f]);
    float cold = c[idx];
    float si = 1.0f / (1.0f + __expf(-zi));
    float sf = 1.0f / (1.0f + __expf(-zf));
    float so = 1.0f / (1.0f + __expf(-zo));
    float cn = sf * cold + si * tanhf(zg);
    float hn = so * tanhf(cn);
    c[idx] = cn;
    ushort hb = f2b(hn);
    h[idx] = hb;
    if (hflip) hflip[(size_t)((row + NV) % NL) * FM + f] = hb;
}

// ---------------- vote output GEMV (bf16 inputs) ------------------------------------
__global__ void vote_out_kernel(const ushort* __restrict__ h1, const ushort* __restrict__ w,
                                const float* __restrict__ b, float* __restrict__ logits_f32,
                                float* __restrict__ out_f32) {
    int gtid = blockIdx.x * blockDim.x + threadIdx.x;
    int wid = gtid >> 6;
    int lane = threadIdx.x & 63;
    if (wid >= NV) return;
    const ushort* hr = h1 + (size_t)wid * 512;
    float s = 0.0f;
    #pragma unroll
    for (int k = 0; k < 8; ++k) s += b2f(hr[lane + 64 * k]) * b2f(w[lane + 64 * k]);
    #pragma unroll
    for (int off = 32; off; off >>= 1) s += __shfl_down(s, off);
    if (lane == 0) {
        float v = s + b[0];
        logits_f32[wid] = v;
        out_f32[wid] = v;
    }
}

// ---------------- per-round clause loss: parallel blocks + one atomic each ----------
__global__ __launch_bounds__(256) void loss_kernel(
    const float* __restrict__ logits, const int* __restrict__ lits,
    float* __restrict__ loss_arr, int r)
{
    __shared__ float sm[256];
    int c = blockIdx.x * 256 + threadIdx.x;
    float t2 = 0.0f;
    if (c < NC) {
        const int* cl = lits + c * 3;
        float s = 0.0f;
        #pragma unroll
        for (int k = 0; k < 3; ++k) {
            int l = cl[k];
            int v = (l > 0 ? l : -l) - 1;
            float sg = (l > 0) ? 1.0f : -1.0f;
            float val = logits[v] * sg;
            s += fmaxf(val, 0.0f) + log1pf(__expf(-fabsf(val)));
        }
        float cv = __expf(-s);
        float t = -logf(1.0f - cv + 1e-8f);
        t2 = t * t;
    }
    sm[threadIdx.x] = t2;
    __syncthreads();
    for (int st = 128; st > 0; st >>= 1) {
        if (threadIdx.x < st) sm[threadIdx.x] += sm[threadIdx.x + st];
        __syncthreads();
    }
    if (threadIdx.x == 0) atomicAdd(&loss_arr[r], sm[0]);
}

__global__ void final_loss_kernel(const float* __restrict__ loss_arr, float* __restrict__ out) {
    if (threadIdx.x == 0 && blockIdx.x == 0) {
        float s = 0.0f;
        for (int r = 0; r < ROUNDS; ++r) s += loss_arr[r];
        out[NV] = s * (1.0f / (float)ROUNDS);
    }
}

extern "C" void kernel_launch(void* const* d_in, const int* in_sizes, int n_in,
                              void* d_out, int out_size, void* d_ws, size_t ws_size,
                              hipStream_t stream) {
    const int* lits = (const int*)d_in[0];
    float* out = (float*)d_out;   // fp32 output: 4000 logits + loss

    const float* Li   = (const float*)d_in[2];
    const float* Ci   = (const float*)d_in[3];
    const float* LCW0 = (const float*)d_in[4];
    const float* LCb0 = (const float*)d_in[5];
    const float* LCW1 = (const float*)d_in[6];
    const float* LCb1 = (const float*)d_in[7];
    const float* LCW2 = (const float*)d_in[8];
    const float* LCb2 = (const float*)d_in[9];
    const float* CLW0 = (const float*)d_in[10];
    const float* CLb0 = (const float*)d_in[11];
    const float* CLW1 = (const float*)d_in[12];
    const float* CLb1 = (const float*)d_in[13];
    const float* CLW2 = (const float*)d_in[14];
    const float* CLb2 = (const float*)d_in[15];
    const float* CWx  = (const float*)d_in[16];
    const float* CWh  = (const float*)d_in[17];
    const float* Cb   = (const float*)d_in[18];
    const float* LWx  = (const float*)d_in[19];
    const float* LWh  = (const float*)d_in[20];
    const float* Lb   = (const float*)d_in[21];
    const float* VW0  = (const float*)d_in[22];
    const float* Vb0  = (const float*)d_in[23];
    const float* VW1  = (const float*)d_in[24];
    const float* Vb1  = (const float*)d_in[25];
    const float* VW2  = (const float*)d_in[26];
    const float* Vb2  = (const float*)d_in[27];
    (void)in_sizes; (void)n_in; (void)out_size; (void)ws_size;

    // ---- ws layout ----
    char* base = (char*)d_ws;
    size_t off = 0;
    auto allocB = [&](size_t bytes) {
        void* p = base + off;
        off += (bytes + 15) & ~(size_t)15;
        return p;
    };
    float*  loss_arr = (float*)allocB(ROUNDS * 4);
    float*  logits   = (float*)allocB(NV * 4);
    float*  lc32     = (float*)allocB((size_t)NL * FM * 4);
    float*  cc32     = (float*)allocB((size_t)NC * FM * 4);
    int*    deg      = (int*)allocB(NL * 4);
    int*    rowptr   = (int*)allocB((NL + 1) * 4);
    int*    nxt      = (int*)allocB(NL * 4);
    int*    ecl      = (int*)allocB(NE * 4);
    // bf16 weights (B^T layouts)
    ushort* LC0t = (ushort*)allocB((size_t)256 * 256 * 2);
    ushort* LC1t = (ushort*)allocB((size_t)256 * 256 * 2);
    ushort* LC2t = (ushort*)allocB((size_t)256 * 256 * 2);
    ushort* CL0t = (ushort*)allocB((size_t)256 * 256 * 2);
    ushort* CL1t = (ushort*)allocB((size_t)256 * 256 * 2);
    ushort* CL2t = (ushort*)allocB((size_t)256 * 256 * 2);
    ushort* CWt  = (ushort*)allocB((size_t)1024 * 512 * 2);   // [1024,512] = [CWx^T | CWh^T]
    ushort* LWt  = (ushort*)allocB((size_t)1024 * 768 * 2);   // [1024,768] = [LWx^T | LWh^T]
    ushort* VW0t = (ushort*)allocB((size_t)512 * 512 * 2);
    ushort* VW1t = (ushort*)allocB((size_t)512 * 512 * 2);
    ushort* vw2  = (ushort*)allocB((size_t)512 * 2);
    // bf16 activations
    ushort* lh16     = (ushort*)allocB((size_t)NL * FM * 2);
    ushort* lhflip16 = (ushort*)allocB((size_t)NL * FM * 2);
    ushort* ch16     = (ushort*)allocB((size_t)NC * FM * 2);
    ushort* lcm16    = (ushort*)allocB((size_t)NC * FM * 2);
    ushort* t0       = (ushort*)allocB((size_t)NC * FM * 2);
    ushort* t1       = (ushort*)allocB((size_t)NC * FM * 2);
    ushort* t2       = (ushort*)allocB((size_t)NC * FM * 2);
    ushort* clm16    = (ushort*)allocB((size_t)NL * FM * 2);
    ushort* v0       = (ushort*)allocB((size_t)NV * 512 * 2);
    ushort* v1       = (ushort*)allocB((size_t)NV * 512 * 2);
    ushort* zC16     = (ushort*)allocB((size_t)NC * 1024 * 2);
    ushort* zL16     = (ushort*)allocB((size_t)NL * 1024 * 2);

    // ---- one-time: weights, states, CSR, loss_arr ----
    auto tw = [&](const float* in, ushort* o, int K, int N, int ldo, int koff) {
        hipLaunchKernelGGL(transpose_w_kernel, dim3((K * N + 255) / 256), dim3(256), 0, stream,
                           in, o, K, N, ldo, koff);
    };
    tw(LCW0, LC0t, 256, 256, 256, 0);
    tw(LCW1, LC1t, 256, 256, 256, 0);
    tw(LCW2, LC2t, 256, 256, 256, 0);
    tw(CLW0, CL0t, 256, 256, 256, 0);
    tw(CLW1, CL1t, 256, 256, 256, 0);
    tw(CLW2, CL2t, 256, 256, 256, 0);
    tw(CWx,  CWt, 256, 1024, 512, 0);
    tw(CWh,  CWt, 256, 1024, 512, 256);
    tw(LWx,  LWt, 512, 1024, 768, 0);
    tw(LWh,  LWt, 256, 1024, 768, 512);
    tw(VW0,  VW0t, 512, 512, 512, 0);
    tw(VW1,  VW1t, 512, 512, 512, 0);
    hipLaunchKernelGGL(f2b_kernel, dim3(2), dim3(256), 0, stream, VW2, vw2, 512);

    hipLaunchKernelGGL(init_lh_kernel, dim3(NL * FM / 256), dim3(256), 0, stream, Li, lh16, lhflip16);
    hipLaunchKernelGGL(init_ch_kernel, dim3(NC * FM / 256), dim3(256), 0, stream, Ci, ch16);
    hipLaunchKernelGGL(zero_kernel, dim3(NL * FM / 256), dim3(256), 0, stream, lc32, NL * FM);
    hipLaunchKernelGGL(zero_kernel, dim3(NC * FM / 256), dim3(256), 0, stream, cc32, NC * FM);
    hipLaunchKernelGGL(zero_kernel, dim3(1), dim3(256), 0, stream, loss_arr, ROUNDS);
    hipLaunchKernelGGL(zero_kernel, dim3((NL + 255) / 256), dim3(256), 0, stream, (float*)deg, NL);
    hipLaunchKernelGGL(csr_count_kernel, dim3((NE + 255) / 256), dim3(256), 0, stream, lits, deg);
    hipLaunchKernelGGL(csr_scan_kernel, dim3(1), dim3(64), 0, stream, deg, rowptr, nxt);
    hipLaunchKernelGGL(csr_fill_kernel, dim3((NE + 255) / 256), dim3(256), 0, stream, lits, nxt, ecl);

    auto gemm = [&](const ushort* A0, int K0, const ushort* A1, int K1,
                    const ushort* A2, int K2, const ushort* Bt, const float* bias,
                    ushort* C, int M, int N, int relu) {
        dim3 g(N / TN, (M + TM - 1) / TM);
        hipLaunchKernelGGL(gemm16_kernel, g, dim3(256), 0, stream,
                           A0, K0, A1, K1, A2, K2, Bt, bias, C, M, N, relu);
    };

    for (int r = 0; r < ROUNDS; ++r) {
        // L -> C message MLP
        gemm(lh16, 256, 0, 0, 0, 0, LC0t, LCb0, t0, NL, 256, 1);
        gemm(t0,   256, 0, 0, 0, 0, LC1t, LCb1, t1, NL, 256, 1);
        gemm(t1,   256, 0, 0, 0, 0, LC2t, LCb2, t2, NL, 256, 0);
        // gather into clauses
        hipLaunchKernelGGL(gather_lc_kernel, dim3(NC * FM / 256), dim3(256), 0, stream,
                           t2, lits, lcm16);
        // clause LSTM: z = [lcm, ch] @ CWt^T + Cb
        gemm(lcm16, 256, ch16, 256, 0, 0, CWt, Cb, zC16, NC, 1024, 0);
        hipLaunchKernelGGL(lstm_update_kernel, dim3(NC * FM / 256), dim3(256), 0, stream,
                           zC16, ch16, (ushort*)0, cc32, NC);
        // C -> L message MLP
        gemm(ch16, 256, 0, 0, 0, 0, CL0t, CLb0, t0, NC, 256, 1);
        gemm(t0,   256, 0, 0, 0, 0, CL1t, CLb1, t1, NC, 256, 1);
        gemm(t1,   256, 0, 0, 0, 0, CL2t, CLb2, t2, NC, 256, 0);
        // CSR gather into literals (replaces zero+atomic scatter+f2b)
        hipLaunchKernelGGL(gather_cl_kernel, dim3(NL * FM / 256), dim3(256), 0, stream,
                           t2, rowptr, ecl, clm16);
        // literal LSTM: z = [clm, flipped, lh] @ LWt^T + Lb
        gemm(clm16, 256, lhflip16, 256, lh16, 256, LWt, Lb, zL16, NL, 1024, 0);
        hipLaunchKernelGGL(lstm_update_kernel, dim3(NL * FM / 256), dim3(256), 0, stream,
                           zL16, lh16, lhflip16, lc32, NL);
        // vote MLP
        gemm(lh16, 256, lh16 + (size_t)NV * FM, 256, 0, 0, VW0t, Vb0, v0, NV, 512, 1);
        gemm(v0, 512, 0, 0, 0, 0, VW1t, Vb1, v1, NV, 512, 1);
        hipLaunchKernelGGL(vote_out_kernel, dim3(NV * 64 / 256), dim3(256), 0, stream,
                           v1, vw2, Vb2, logits, out);
        hipLaunchKernelGGL(loss_kernel, dim3((NC + 255) / 256), dim3(256), 0, stream,
                           logits, lits, loss_arr, r);
    }

    hipLaunchKernelGGL(final_loss_kernel, dim3(1), dim3(64), 0, stream, loss_arr, out);
}

// Round 9
// 6921.518 us; speedup vs baseline: 7.0393x; 1.4267x over previous
//
#include <hip/hip_runtime.h>
#include <hip/hip_bf16.h>

#define NV 4000
#define NL 8000
#define NC 16800
#define NE 50400
#define FM 256
#define ROUNDS 32

typedef short s16x8 __attribute__((ext_vector_type(8)));
typedef __bf16 b16x8 __attribute__((ext_vector_type(8)));
typedef float f32x4 __attribute__((ext_vector_type(4)));
union V8 { s16x8 s; b16x8 b; ushort u[8]; };

using gaddr_t = const void __attribute__((address_space(1)))*;
using laddr_t = void __attribute__((address_space(3)))*;

__device__ __forceinline__ float b2f(ushort u) {
    union { uint i; float f; } v; v.i = ((uint)u) << 16; return v.f;
}
__device__ __forceinline__ ushort f2b(float f) {
    __hip_bfloat16 h = __float2bfloat16(f);
    return *(ushort*)&h;
}

// ---------------- utility ----------------
__global__ void zero_kernel(float* __restrict__ p, int n) {
    int i = blockIdx.x * blockDim.x + threadIdx.x;
    if (i < n) p[i] = 0.0f;
}
__global__ void f2b_kernel(const float* __restrict__ src, ushort* __restrict__ dst, int n) {
    int i = blockIdx.x * blockDim.x + threadIdx.x;
    if (i < n) dst[i] = f2b(src[i]);
}
// W [K,N] fp32 -> out [N', ldo] bf16 at k-offset koff; perm: row = (n&255)*4 + (n>>8)
__global__ void transpose_w_kernel(const float* __restrict__ in, ushort* __restrict__ out,
                                   int K, int N, int ldo, int koff, int perm) {
    int idx = blockIdx.x * blockDim.x + threadIdx.x;
    if (idx >= K * N) return;
    int n = idx / K, k = idx - n * K;
    int row = perm ? ((n & 255) * 4 + (n >> 8)) : n;
    out[(size_t)row * ldo + koff + k] = f2b(in[(size_t)k * N + n]);
}
__global__ void permute_bias_kernel(const float* __restrict__ b, float* __restrict__ bp) {
    int n = blockIdx.x * blockDim.x + threadIdx.x;
    if (n < 1024) bp[(n & 255) * 4 + (n >> 8)] = b[n];
}

// ---------------- init states ----------------
__global__ void init_lh_kernel(const float* __restrict__ Li, ushort* __restrict__ lh,
                               ushort* __restrict__ lhflip) {
    int idx = blockIdx.x * blockDim.x + threadIdx.x;
    if (idx < NL * FM) {
        ushort v = f2b(Li[idx & (FM - 1)] * (1.0f / 16.0f));
        lh[idx] = v; lhflip[idx] = v;
    }
}
__global__ void init_ch_kernel(const float* __restrict__ Ci, ushort* __restrict__ ch) {
    int idx = blockIdx.x * blockDim.x + threadIdx.x;
    if (idx < NC * FM) ch[idx] = f2b(Ci[idx & (FM - 1)] * (1.0f / 16.0f));
}

// ---------------- CSR build ----------------
__global__ void csr_count_kernel(const int* __restrict__ lits, int* __restrict__ deg) {
    int e = blockIdx.x * blockDim.x + threadIdx.x;
    if (e >= NE) return;
    int l = lits[e];
    int v = (l > 0 ? l : -l) - 1;
    int li = (l > 0) ? v : NV + v;
    atomicAdd(&deg[li], 1);
}
__global__ void csr_scan_kernel(const int* __restrict__ deg, int* __restrict__ rowptr,
                                int* __restrict__ nxt) {
    if (threadIdx.x == 0 && blockIdx.x == 0) {
        int acc = 0;
        for (int i = 0; i < NL; ++i) { rowptr[i] = acc; nxt[i] = acc; acc += deg[i]; }
        rowptr[NL] = acc;
    }
}
__global__ void csr_fill_kernel(const int* __restrict__ lits, int* __restrict__ nxt,
                                int* __restrict__ ecl) {
    int e = blockIdx.x * blockDim.x + threadIdx.x;
    if (e >= NE) return;
    int l = lits[e];
    int v = (l > 0 ? l : -l) - 1;
    int li = (l > 0) ? v : NV + v;
    int pos = atomicAdd(&nxt[li], 1);
    ecl[pos] = e / 3;
}

// =========== MFMA bf16 GEMM 128x128 tile (for N multiple of 128) ===========
#define BKT 64
__global__ __launch_bounds__(256) void gemm16_kernel(
    const ushort* __restrict__ A0, int K0,
    const ushort* __restrict__ A1, int K1,
    const ushort* __restrict__ Bt, const float* __restrict__ bias,
    ushort* __restrict__ C, int M, int N, int relu)
{
    __shared__ __align__(16) ushort Al[128 * BKT];
    __shared__ __align__(16) ushort Bl[128 * BKT];
    const int Ktot = K0 + K1;
    const int tid = threadIdx.x;
    const int rowBase = blockIdx.y * 128, colBase = blockIdx.x * 128;
    const int lane = tid & 63, wid = tid >> 6;
    const int wm = (wid >> 1) * 64, wn = (wid & 1) * 64;
    const int lr = lane >> 3, ql = (lane & 7) ^ lr;

    f32x4 acc[4][4];
    #pragma unroll
    for (int i = 0; i < 4; ++i)
        #pragma unroll
        for (int j = 0; j < 4; ++j) acc[i][j] = (f32x4){0.f, 0.f, 0.f, 0.f};

    for (int k0 = 0; k0 < Ktot; k0 += BKT) {
        const ushort* As; int ks, lda;
        if (k0 < K0) { As = A0; ks = k0; lda = K0; }
        else         { As = A1; ks = k0 - K0; lda = K1; }
        __syncthreads();
        #pragma unroll
        for (int t = 0; t < 4; ++t) {
            int rloc = (wid * 4 + t) * 8 + lr;
            int ga = rowBase + rloc; if (ga > M - 1) ga = M - 1;
            __builtin_amdgcn_global_load_lds((gaddr_t)(As + (size_t)ga * lda + ks + ql * 8),
                                             (laddr_t)&Al[(wid * 4 + t) * 512], 16, 0, 0);
            __builtin_amdgcn_global_load_lds((gaddr_t)(Bt + (size_t)(colBase + rloc) * Ktot + k0 + ql * 8),
                                             (laddr_t)&Bl[(wid * 4 + t) * 512], 16, 0, 0);
        }
        __syncthreads();
        const int cl = lane & 15, kg = lane >> 4;
        #pragma unroll
        for (int s = 0; s < 2; ++s) {
            V8 af[4], bf[4];
            #pragma unroll
            for (int i = 0; i < 4; ++i) {
                int m = wm + i * 16 + cl;
                af[i].s = *(const s16x8*)&Al[m * BKT + (((s * 4 + kg) ^ (m & 7)) * 8)];
            }
            #pragma unroll
            for (int j = 0; j < 4; ++j) {
                int n = wn + j * 16 + cl;
                bf[j].s = *(const s16x8*)&Bl[n * BKT + (((s * 4 + kg) ^ (n & 7)) * 8)];
            }
            #pragma unroll
            for (int i = 0; i < 4; ++i)
                #pragma unroll
                for (int j = 0; j < 4; ++j)
                    acc[i][j] = __builtin_amdgcn_mfma_f32_16x16x32_bf16(af[i].b, bf[j].b,
                                                                        acc[i][j], 0, 0, 0);
        }
    }
    const int rq = (lane >> 4) * 4, cl = lane & 15;
    #pragma unroll
    for (int i = 0; i < 4; ++i)
        #pragma unroll
        for (int r = 0; r < 4; ++r) {
            int grow = rowBase + wm + i * 16 + rq + r;
            if (grow >= M) continue;
            #pragma unroll
            for (int j = 0; j < 4; ++j) {
                int gcol = colBase + wn + j * 16 + cl;
                float v = acc[i][j][r] + bias[gcol];
                if (relu) v = fmaxf(v, 0.0f);
                C[(size_t)grow * N + gcol] = f2b(v);
            }
        }
}

// =========== MFMA bf16 GEMM 128x64 tile (more blocks for small N) ===========
__global__ __launch_bounds__(256) void gemm16_n64_kernel(
    const ushort* __restrict__ A0, int K0,
    const ushort* __restrict__ A1, int K1,
    const ushort* __restrict__ Bt, const float* __restrict__ bias,
    ushort* __restrict__ C, int M, int N, int relu)
{
    __shared__ __align__(16) ushort Al[128 * BKT];
    __shared__ __align__(16) ushort Bl[64 * BKT];
    const int Ktot = K0 + K1;
    const int tid = threadIdx.x;
    const int rowBase = blockIdx.y * 128, colBase = blockIdx.x * 64;
    const int lane = tid & 63, wid = tid >> 6;
    const int wm = (wid & 1) * 64, wn = (wid >> 1) * 32;
    const int lr = lane >> 3, ql = (lane & 7) ^ lr;

    f32x4 acc[4][2];
    #pragma unroll
    for (int i = 0; i < 4; ++i)
        #pragma unroll
        for (int j = 0; j < 2; ++j) acc[i][j] = (f32x4){0.f, 0.f, 0.f, 0.f};

    for (int k0 = 0; k0 < Ktot; k0 += BKT) {
        const ushort* As; int ks, lda;
        if (k0 < K0) { As = A0; ks = k0; lda = K0; }
        else         { As = A1; ks = k0 - K0; lda = K1; }
        __syncthreads();
        #pragma unroll
        for (int t = 0; t < 4; ++t) {
            int rloc = (wid * 4 + t) * 8 + lr;
            int ga = rowBase + rloc; if (ga > M - 1) ga = M - 1;
            __builtin_amdgcn_global_load_lds((gaddr_t)(As + (size_t)ga * lda + ks + ql * 8),
                                             (laddr_t)&Al[(wid * 4 + t) * 512], 16, 0, 0);
        }
        #pragma unroll
        for (int t = 0; t < 2; ++t) {
            int rloc = (wid * 2 + t) * 8 + lr;
            __builtin_amdgcn_global_load_lds((gaddr_t)(Bt + (size_t)(colBase + rloc) * Ktot + k0 + ql * 8),
                                             (laddr_t)&Bl[(wid * 2 + t) * 512], 16, 0, 0);
        }
        __syncthreads();
        const int cl = lane & 15, kg = lane >> 4;
        #pragma unroll
        for (int s = 0; s < 2; ++s) {
            V8 af[4], bf[2];
            #pragma unroll
            for (int i = 0; i < 4; ++i) {
                int m = wm + i * 16 + cl;
                af[i].s = *(const s16x8*)&Al[m * BKT + (((s * 4 + kg) ^ (m & 7)) * 8)];
            }
            #pragma unroll
            for (int j = 0; j < 2; ++j) {
                int n = wn + j * 16 + cl;
                bf[j].s = *(const s16x8*)&Bl[n * BKT + (((s * 4 + kg) ^ (n & 7)) * 8)];
            }
            #pragma unroll
            for (int i = 0; i < 4; ++i)
                #pragma unroll
                for (int j = 0; j < 2; ++j)
                    acc[i][j] = __builtin_amdgcn_mfma_f32_16x16x32_bf16(af[i].b, bf[j].b,
                                                                        acc[i][j], 0, 0, 0);
        }
    }
    const int rq = (lane >> 4) * 4, cl = lane & 15;
    #pragma unroll
    for (int i = 0; i < 4; ++i)
        #pragma unroll
        for (int r = 0; r < 4; ++r) {
            int grow = rowBase + wm + i * 16 + rq + r;
            if (grow >= M) continue;
            #pragma unroll
            for (int j = 0; j < 2; ++j) {
                int gcol = colBase + wn + j * 16 + cl;
                float v = acc[i][j][r] + bias[gcol];
                if (relu) v = fmaxf(v, 0.0f);
                C[(size_t)grow * N + gcol] = f2b(v);
            }
        }
}

// =========== Fused z-GEMM + LSTM (N=1024, gate-interleaved weights) ===========
// z'[:,4f+g] layout; epilogue: z tile -> LDS (reuse staging), per-feature LSTM.
__global__ __launch_bounds__(256) void gemm_lstm_kernel(
    const ushort* __restrict__ A0, int K0,
    const ushort* __restrict__ A1, int K1,
    const ushort* __restrict__ A2, int K2,
    const ushort* __restrict__ Bt, const float* __restrict__ biasP,
    float* __restrict__ c32, ushort* __restrict__ h_out,
    ushort* __restrict__ hflip_out, int M)
{
    __shared__ __align__(16) ushort smem[2 * 128 * BKT];   // staging; reused as zt[128][128]
    ushort* Al = smem;
    ushort* Bl = smem + 128 * BKT;
    const int Ktot = K0 + K1 + K2;
    const int tid = threadIdx.x;
    const int rowBase = blockIdx.y * 128, colBase = blockIdx.x * 128;
    const int lane = tid & 63, wid = tid >> 6;
    const int wm = (wid >> 1) * 64, wn = (wid & 1) * 64;
    const int lr = lane >> 3, ql = (lane & 7) ^ lr;

    f32x4 acc[4][4];
    #pragma unroll
    for (int i = 0; i < 4; ++i)
        #pragma unroll
        for (int j = 0; j < 4; ++j) acc[i][j] = (f32x4){0.f, 0.f, 0.f, 0.f};

    for (int k0 = 0; k0 < Ktot; k0 += BKT) {
        const ushort* As; int ks, lda;
        if (k0 < K0)           { As = A0; ks = k0;           lda = K0; }
        else if (k0 < K0 + K1) { As = A1; ks = k0 - K0;      lda = K1; }
        else                   { As = A2; ks = k0 - K0 - K1; lda = K2; }
        __syncthreads();
        #pragma unroll
        for (int t = 0; t < 4; ++t) {
            int rloc = (wid * 4 + t) * 8 + lr;
            int ga = rowBase + rloc; if (ga > M - 1) ga = M - 1;
            __builtin_amdgcn_global_load_lds((gaddr_t)(As + (size_t)ga * lda + ks + ql * 8),
                                             (laddr_t)&Al[(wid * 4 + t) * 512], 16, 0, 0);
            __builtin_amdgcn_global_load_lds((gaddr_t)(Bt + (size_t)(colBase + rloc) * Ktot + k0 + ql * 8),
                                             (laddr_t)&Bl[(wid * 4 + t) * 512], 16, 0, 0);
        }
        __syncthreads();
        const int cl = lane & 15, kg = lane >> 4;
        #pragma unroll
        for (int s = 0; s < 2; ++s) {
            V8 af[4], bf[4];
            #pragma unroll
            for (int i = 0; i < 4; ++i) {
                int m = wm + i * 16 + cl;
                af[i].s = *(const s16x8*)&Al[m * BKT + (((s * 4 + kg) ^ (m & 7)) * 8)];
            }
            #pragma unroll
            for (int j = 0; j < 4; ++j) {
                int n = wn + j * 16 + cl;
                bf[j].s = *(const s16x8*)&Bl[n * BKT + (((s * 4 + kg) ^ (n & 7)) * 8)];
            }
            #pragma unroll
            for (int i = 0; i < 4; ++i)
                #pragma unroll
                for (int j = 0; j < 4; ++j)
                    acc[i][j] = __builtin_amdgcn_mfma_f32_16x16x32_bf16(af[i].b, bf[j].b,
                                                                        acc[i][j], 0, 0, 0);
        }
    }
    // ---- epilogue: z tile (bf16, post-bias) into LDS ----
    __syncthreads();     // all staging-LDS reads done before overwrite
    {
        const int rq = (lane >> 4) * 4, cl = lane & 15;
        #pragma unroll
        for (int i = 0; i < 4; ++i)
            #pragma unroll
            for (int r = 0; r < 4; ++r) {
                int rl = wm + i * 16 + rq + r;
                #pragma unroll
                for (int j = 0; j < 4; ++j) {
                    int clc = wn + j * 16 + cl;
                    smem[rl * 128 + clc] = f2b(acc[i][j][r] + biasP[colBase + clc]);
                }
            }
    }
    __syncthreads();
    // ---- LSTM: 32 features x 128 rows per block ----
    const int fl = tid & 31, rg = tid >> 5;
    const int fglob = (colBase >> 2) + fl;
    #pragma unroll
    for (int k = 0; k < 16; ++k) {
        int rl = rg + 8 * k;
        int grow = rowBase + rl;
        if (grow >= M) continue;
        ushort4 g4 = *(const ushort4*)&smem[rl * 128 + fl * 4];
        float zi = b2f(g4.x), zf = b2f(g4.y), zg = b2f(g4.z), zo = b2f(g4.w);
        size_t ci = (size_t)grow * FM + fglob;
        float cold = c32[ci];
        float si = 1.0f / (1.0f + __expf(-zi));
        float sf = 1.0f / (1.0f + __expf(-zf));
        float so = 1.0f / (1.0f + __expf(-zo));
        float cn = sf * cold + si * tanhf(zg);
        float hn = so * tanhf(cn);
        c32[ci] = cn;
        ushort hb = f2b(hn);
        h_out[ci] = hb;
        if (hflip_out) hflip_out[(size_t)((grow + NV) % NL) * FM + fglob] = hb;
    }
}

// ---------------- gather (vectorized x8): lcm[c] = sum_k lc_pre[lit(c,k)] -----------
__global__ void gather_lc8_kernel(const ushort* __restrict__ pre, const int* __restrict__ lits,
                                  ushort* __restrict__ out) {
    int idx = blockIdx.x * blockDim.x + threadIdx.x;
    if (idx >= NC * 32) return;
    int c = idx >> 5, f8 = (idx & 31) * 8;
    const int* cl = lits + c * 3;
    float s[8] = {};
    #pragma unroll
    for (int k = 0; k < 3; ++k) {
        int l = cl[k];
        int v = (l > 0 ? l : -l) - 1;
        int li = (l > 0) ? v : NV + v;
        V8 x; x.s = *(const s16x8*)&pre[(size_t)li * FM + f8];
        #pragma unroll
        for (int e = 0; e < 8; ++e) s[e] += b2f(x.u[e]);
    }
    V8 o;
    #pragma unroll
    for (int e = 0; e < 8; ++e) o.u[e] = f2b(s[e]);
    *(s16x8*)&out[(size_t)c * FM + f8] = o.s;
}

// ---------------- CSR gather (vectorized x8) ----------------------------------------
__global__ void gather_cl8_kernel(const ushort* __restrict__ pre, const int* __restrict__ rowptr,
                                  const int* __restrict__ ecl, ushort* __restrict__ out) {
    int idx = blockIdx.x * blockDim.x + threadIdx.x;
    if (idx >= NL * 32) return;
    int li = idx >> 5, f8 = (idx & 31) * 8;
    int j0 = rowptr[li], j1 = rowptr[li + 1];
    float s[8] = {};
    for (int j = j0; j < j1; ++j) {
        V8 x; x.s = *(const s16x8*)&pre[(size_t)ecl[j] * FM + f8];
        #pragma unroll
        for (int e = 0; e < 8; ++e) s[e] += b2f(x.u[e]);
    }
    V8 o;
    #pragma unroll
    for (int e = 0; e < 8; ++e) o.u[e] = f2b(s[e]);
    *(s16x8*)&out[(size_t)li * FM + f8] = o.s;
}

// ---------------- vote output GEMV ----------------
__global__ void vote_out_kernel(const ushort* __restrict__ h1, const ushort* __restrict__ w,
                                const float* __restrict__ b, float* __restrict__ logits_f32,
                                float* __restrict__ out_f32) {
    int gtid = blockIdx.x * blockDim.x + threadIdx.x;
    int wid = gtid >> 6;
    int lane = threadIdx.x & 63;
    if (wid >= NV) return;
    const ushort* hr = h1 + (size_t)wid * 512;
    float s = 0.0f;
    #pragma unroll
    for (int k = 0; k < 8; ++k) s += b2f(hr[lane + 64 * k]) * b2f(w[lane + 64 * k]);
    #pragma unroll
    for (int off = 32; off; off >>= 1) s += __shfl_down(s, off);
    if (lane == 0) {
        float v = s + b[0];
        logits_f32[wid] = v;
        out_f32[wid] = v;
    }
}

// ---------------- per-round clause loss ----------------
__global__ __launch_bounds__(256) void loss_kernel(
    const float* __restrict__ logits, const int* __restrict__ lits,
    float* __restrict__ loss_arr, int r)
{
    __shared__ float sm[256];
    int c = blockIdx.x * 256 + threadIdx.x;
    float t2 = 0.0f;
    if (c < NC) {
        const int* cl = lits + c * 3;
        float s = 0.0f;
        #pragma unroll
        for (int k = 0; k < 3; ++k) {
            int l = cl[k];
            int v = (l > 0 ? l : -l) - 1;
            float sg = (l > 0) ? 1.0f : -1.0f;
            float val = logits[v] * sg;
            s += fmaxf(val, 0.0f) + log1pf(__expf(-fabsf(val)));
        }
        float cv = __expf(-s);
        float t = -logf(1.0f - cv + 1e-8f);
        t2 = t * t;
    }
    sm[threadIdx.x] = t2;
    __syncthreads();
    for (int st = 128; st > 0; st >>= 1) {
        if (threadIdx.x < st) sm[threadIdx.x] += sm[threadIdx.x + st];
        __syncthreads();
    }
    if (threadIdx.x == 0) atomicAdd(&loss_arr[r], sm[0]);
}

__global__ void final_loss_kernel(const float* __restrict__ loss_arr, float* __restrict__ out) {
    if (threadIdx.x == 0 && blockIdx.x == 0) {
        float s = 0.0f;
        for (int r = 0; r < ROUNDS; ++r) s += loss_arr[r];
        out[NV] = s * (1.0f / (float)ROUNDS);
    }
}

extern "C" void kernel_launch(void* const* d_in, const int* in_sizes, int n_in,
                              void* d_out, int out_size, void* d_ws, size_t ws_size,
                              hipStream_t stream) {
    const int* lits = (const int*)d_in[0];
    float* out = (float*)d_out;

    const float* Li   = (const float*)d_in[2];
    const float* Ci   = (const float*)d_in[3];
    const float* LCW0 = (const float*)d_in[4];
    const float* LCb0 = (const float*)d_in[5];
    const float* LCW1 = (const float*)d_in[6];
    const float* LCb1 = (const float*)d_in[7];
    const float* LCW2 = (const float*)d_in[8];
    const float* LCb2 = (const float*)d_in[9];
    const float* CLW0 = (const float*)d_in[10];
    const float* CLb0 = (const float*)d_in[11];
    const float* CLW1 = (const float*)d_in[12];
    const float* CLb1 = (const float*)d_in[13];
    const float* CLW2 = (const float*)d_in[14];
    const float* CLb2 = (const float*)d_in[15];
    const float* CWx  = (const float*)d_in[16];
    const float* CWh  = (const float*)d_in[17];
    const float* Cb   = (const float*)d_in[18];
    const float* LWx  = (const float*)d_in[19];
    const float* LWh  = (const float*)d_in[20];
    const float* Lb   = (const float*)d_in[21];
    const float* VW0  = (const float*)d_in[22];
    const float* Vb0  = (const float*)d_in[23];
    const float* VW1  = (const float*)d_in[24];
    const float* Vb1  = (const float*)d_in[25];
    const float* VW2  = (const float*)d_in[26];
    const float* Vb2  = (const float*)d_in[27];
    (void)in_sizes; (void)n_in; (void)out_size; (void)ws_size;

    // ---- ws layout ----
    char* base = (char*)d_ws;
    size_t off = 0;
    auto allocB = [&](size_t bytes) {
        void* p = base + off;
        off += (bytes + 15) & ~(size_t)15;
        return p;
    };
    float*  loss_arr = (float*)allocB(ROUNDS * 4);
    float*  logits   = (float*)allocB(NV * 4);
    float*  lc32     = (float*)allocB((size_t)NL * FM * 4);
    float*  cc32     = (float*)allocB((size_t)NC * FM * 4);
    float*  Cb_p     = (float*)allocB(1024 * 4);
    float*  Lb_p     = (float*)allocB(1024 * 4);
    int*    deg      = (int*)allocB(NL * 4);
    int*    rowptr   = (int*)allocB((NL + 1) * 4);
    int*    nxt      = (int*)allocB(NL * 4);
    int*    ecl      = (int*)allocB(NE * 4);
    ushort* LC0t = (ushort*)allocB((size_t)256 * 256 * 2);
    ushort* LC1t = (ushort*)allocB((size_t)256 * 256 * 2);
    ushort* LC2t = (ushort*)allocB((size_t)256 * 256 * 2);
    ushort* CL0t = (ushort*)allocB((size_t)256 * 256 * 2);
    ushort* CL1t = (ushort*)allocB((size_t)256 * 256 * 2);
    ushort* CL2t = (ushort*)allocB((size_t)256 * 256 * 2);
    ushort* CWt  = (ushort*)allocB((size_t)1024 * 512 * 2);   // gate-interleaved rows
    ushort* LWt  = (ushort*)allocB((size_t)1024 * 768 * 2);
    ushort* VW0t = (ushort*)allocB((size_t)512 * 512 * 2);
    ushort* VW1t = (ushort*)allocB((size_t)512 * 512 * 2);
    ushort* vw2  = (ushort*)allocB((size_t)512 * 2);
    ushort* lh_a = (ushort*)allocB((size_t)NL * FM * 2);
    ushort* lh_b = (ushort*)allocB((size_t)NL * FM * 2);
    ushort* lf_a = (ushort*)allocB((size_t)NL * FM * 2);
    ushort* lf_b = (ushort*)allocB((size_t)NL * FM * 2);
    ushort* ch_a = (ushort*)allocB((size_t)NC * FM * 2);
    ushort* ch_b = (ushort*)allocB((size_t)NC * FM * 2);
    ushort* lcm16 = (ushort*)allocB((size_t)NC * FM * 2);
    ushort* clm16 = (ushort*)allocB((size_t)NL * FM * 2);
    ushort* t0    = (ushort*)allocB((size_t)NC * FM * 2);
    ushort* t1    = (ushort*)allocB((size_t)NC * FM * 2);
    ushort* t2    = (ushort*)allocB((size_t)NC * FM * 2);
    ushort* v0    = (ushort*)allocB((size_t)NV * 512 * 2);
    ushort* v1    = (ushort*)allocB((size_t)NV * 512 * 2);

    // ---- setup: weights, bias permutes, states, CSR ----
    auto tw = [&](const float* in, ushort* o, int K, int N, int ldo, int koff, int perm) {
        hipLaunchKernelGGL(transpose_w_kernel, dim3((K * N + 255) / 256), dim3(256), 0, stream,
                           in, o, K, N, ldo, koff, perm);
    };
    tw(LCW0, LC0t, 256, 256, 256, 0, 0);
    tw(LCW1, LC1t, 256, 256, 256, 0, 0);
    tw(LCW2, LC2t, 256, 256, 256, 0, 0);
    tw(CLW0, CL0t, 256, 256, 256, 0, 0);
    tw(CLW1, CL1t, 256, 256, 256, 0, 0);
    tw(CLW2, CL2t, 256, 256, 256, 0, 0);
    tw(CWx,  CWt, 256, 1024, 512, 0, 1);
    tw(CWh,  CWt, 256, 1024, 512, 256, 1);
    tw(LWx,  LWt, 512, 1024, 768, 0, 1);
    tw(LWh,  LWt, 256, 1024, 768, 512, 1);
    tw(VW0,  VW0t, 512, 512, 512, 0, 0);
    tw(VW1,  VW1t, 512, 512, 512, 0, 0);
    hipLaunchKernelGGL(f2b_kernel, dim3(2), dim3(256), 0, stream, VW2, vw2, 512);
    hipLaunchKernelGGL(permute_bias_kernel, dim3(4), dim3(256), 0, stream, Cb, Cb_p);
    hipLaunchKernelGGL(permute_bias_kernel, dim3(4), dim3(256), 0, stream, Lb, Lb_p);

    hipLaunchKernelGGL(init_lh_kernel, dim3(NL * FM / 256), dim3(256), 0, stream, Li, lh_a, lf_a);
    hipLaunchKernelGGL(init_ch_kernel, dim3(NC * FM / 256), dim3(256), 0, stream, Ci, ch_a);
    hipLaunchKernelGGL(zero_kernel, dim3(NL * FM / 256), dim3(256), 0, stream, lc32, NL * FM);
    hipLaunchKernelGGL(zero_kernel, dim3(NC * FM / 256), dim3(256), 0, stream, cc32, NC * FM);
    hipLaunchKernelGGL(zero_kernel, dim3(1), dim3(256), 0, stream, loss_arr, ROUNDS);
    hipLaunchKernelGGL(zero_kernel, dim3((NL + 255) / 256), dim3(256), 0, stream, (float*)deg, NL);
    hipLaunchKernelGGL(csr_count_kernel, dim3((NE + 255) / 256), dim3(256), 0, stream, lits, deg);
    hipLaunchKernelGGL(csr_scan_kernel, dim3(1), dim3(64), 0, stream, deg, rowptr, nxt);
    hipLaunchKernelGGL(csr_fill_kernel, dim3((NE + 255) / 256), dim3(256), 0, stream, lits, nxt, ecl);

    auto gemm128 = [&](const ushort* A0, int K0, const ushort* A1, int K1,
                       const ushort* Bt, const float* bias, ushort* C, int M, int N, int relu) {
        hipLaunchKernelGGL(gemm16_kernel, dim3(N / 128, (M + 127) / 128), dim3(256), 0, stream,
                           A0, K0, A1, K1, Bt, bias, C, M, N, relu);
    };
    auto gemm64 = [&](const ushort* A0, int K0, const ushort* A1, int K1,
                      const ushort* Bt, const float* bias, ushort* C, int M, int N, int relu) {
        hipLaunchKernelGGL(gemm16_n64_kernel, dim3(N / 64, (M + 127) / 128), dim3(256), 0, stream,
                           A0, K0, A1, K1, Bt, bias, C, M, N, relu);
    };

    ushort *lh_c = lh_a, *lh_n = lh_b, *lf_c = lf_a, *lf_n = lf_b, *ch_c = ch_a, *ch_n = ch_b;

    for (int r = 0; r < ROUNDS; ++r) {
        // L -> C message MLP (252-block grids)
        gemm64(lh_c, 256, 0, 0, LC0t, LCb0, t0, NL, 256, 1);
        gemm64(t0,   256, 0, 0, LC1t, LCb1, t1, NL, 256, 1);
        gemm64(t1,   256, 0, 0, LC2t, LCb2, t2, NL, 256, 0);
        // gather into clauses
        hipLaunchKernelGGL(gather_lc8_kernel, dim3(NC * 32 / 256), dim3(256), 0, stream,
                           t2, lits, lcm16);
        // fused clause z-GEMM + LSTM (writes ch_n, updates cc32 in place)
        hipLaunchKernelGGL(gemm_lstm_kernel, dim3(8, (NC + 127) / 128), dim3(256), 0, stream,
                           lcm16, 256, ch_c, 256, (const ushort*)0, 0,
                           CWt, Cb_p, cc32, ch_n, (ushort*)0, NC);
        // C -> L message MLP
        gemm128(ch_n, 256, 0, 0, CL0t, CLb0, t0, NC, 256, 1);
        gemm128(t0,   256, 0, 0, CL1t, CLb1, t1, NC, 256, 1);
        gemm128(t1,   256, 0, 0, CL2t, CLb2, t2, NC, 256, 0);
        // CSR gather into literals
        hipLaunchKernelGGL(gather_cl8_kernel, dim3(NL * 32 / 256), dim3(256), 0, stream,
                           t2, rowptr, ecl, clm16);
        // fused literal z-GEMM + LSTM (writes lh_n + lf_n, updates lc32 in place)
        hipLaunchKernelGGL(gemm_lstm_kernel, dim3(8, (NL + 127) / 128), dim3(256), 0, stream,
                           clm16, 256, lf_c, 256, lh_c, 256,
                           LWt, Lb_p, lc32, lh_n, lf_n, NL);
        // vote MLP (256-block grids)
        gemm64(lh_n, 256, lh_n + (size_t)NV * FM, 256, VW0t, Vb0, v0, NV, 512, 1);
        gemm64(v0, 512, 0, 0, VW1t, Vb1, v1, NV, 512, 1);
        hipLaunchKernelGGL(vote_out_kernel, dim3(NV * 64 / 256), dim3(256), 0, stream,
                           v1, vw2, Vb2, logits, out);
        hipLaunchKernelGGL(loss_kernel, dim3((NC + 255) / 256), dim3(256), 0, stream,
                           logits, lits, loss_arr, r);
        // swap state buffers
        ushort* tswap;
        tswap = lh_c; lh_c = lh_n; lh_n = tswap;
        tswap = lf_c; lf_c = lf_n; lf_n = tswap;
        tswap = ch_c; ch_c = ch_n; ch_n = tswap;
    }

    hipLaunchKernelGGL(final_loss_kernel, dim3(1), dim3(64), 0, stream, loss_arr, out);
}

// Round 10
// 5780.586 us; speedup vs baseline: 8.4286x; 1.1974x over previous
//
#include <hip/hip_runtime.h>
#include <hip/hip_bf16.h>

#define NV 4000
#define NL 8000
#define NC 16800
#define NE 50400
#define FM 256
#define ROUNDS 32

typedef short s16x8 __attribute__((ext_vector_type(8)));
typedef __bf16 b16x8 __attribute__((ext_vector_type(8)));
typedef float f32x4 __attribute__((ext_vector_type(4)));
union V8 { s16x8 s; b16x8 b; ushort u[8]; };

using gaddr_t = const void __attribute__((address_space(1)))*;
using laddr_t = void __attribute__((address_space(3)))*;

__device__ __forceinline__ float b2f(ushort u) {
    union { uint i; float f; } v; v.i = ((uint)u) << 16; return v.f;
}
__device__ __forceinline__ ushort f2b(float f) {
    __hip_bfloat16 h = __float2bfloat16(f);
    return *(ushort*)&h;
}

// ---------------- utility ----------------
__global__ void zero_kernel(float* __restrict__ p, int n) {
    int i = blockIdx.x * blockDim.x + threadIdx.x;
    if (i < n) p[i] = 0.0f;
}
__global__ void f2b_kernel(const float* __restrict__ src, ushort* __restrict__ dst, int n) {
    int i = blockIdx.x * blockDim.x + threadIdx.x;
    if (i < n) dst[i] = f2b(src[i]);
}
// W [K,N] fp32 -> out [N', ldo] bf16 at k-offset koff; perm: row = (n&255)*4 + (n>>8)
__global__ void transpose_w_kernel(const float* __restrict__ in, ushort* __restrict__ out,
                                   int K, int N, int ldo, int koff, int perm) {
    int idx = blockIdx.x * blockDim.x + threadIdx.x;
    if (idx >= K * N) return;
    int n = idx / K, k = idx - n * K;
    int row = perm ? ((n & 255) * 4 + (n >> 8)) : n;
    out[(size_t)row * ldo + koff + k] = f2b(in[(size_t)k * N + n]);
}
__global__ void permute_bias_kernel(const float* __restrict__ b, float* __restrict__ bp) {
    int n = blockIdx.x * blockDim.x + threadIdx.x;
    if (n < 1024) bp[(n & 255) * 4 + (n >> 8)] = b[n];
}

// ---------------- init states ----------------
__global__ void init_lh_kernel(const float* __restrict__ Li, ushort* __restrict__ lh,
                               ushort* __restrict__ lhflip) {
    int idx = blockIdx.x * blockDim.x + threadIdx.x;
    if (idx < NL * FM) {
        ushort v = f2b(Li[idx & (FM - 1)] * (1.0f / 16.0f));
        lh[idx] = v; lhflip[idx] = v;
    }
}
__global__ void init_ch_kernel(const float* __restrict__ Ci, ushort* __restrict__ ch) {
    int idx = blockIdx.x * blockDim.x + threadIdx.x;
    if (idx < NC * FM) ch[idx] = f2b(Ci[idx & (FM - 1)] * (1.0f / 16.0f));
}

// ---------------- CSR build ----------------
__global__ void csr_count_kernel(const int* __restrict__ lits, int* __restrict__ deg) {
    int e = blockIdx.x * blockDim.x + threadIdx.x;
    if (e >= NE) return;
    int l = lits[e];
    int v = (l > 0 ? l : -l) - 1;
    int li = (l > 0) ? v : NV + v;
    atomicAdd(&deg[li], 1);
}
__global__ void csr_scan_kernel(const int* __restrict__ deg, int* __restrict__ rowptr,
                                int* __restrict__ nxt) {
    if (threadIdx.x == 0 && blockIdx.x == 0) {
        int acc = 0;
        for (int i = 0; i < NL; ++i) { rowptr[i] = acc; nxt[i] = acc; acc += deg[i]; }
        rowptr[NL] = acc;
    }
}
__global__ void csr_fill_kernel(const int* __restrict__ lits, int* __restrict__ nxt,
                                int* __restrict__ ecl) {
    int e = blockIdx.x * blockDim.x + threadIdx.x;
    if (e >= NE) return;
    int l = lits[e];
    int v = (l > 0 ? l : -l) - 1;
    int li = (l > 0) ? v : NV + v;
    int pos = atomicAdd(&nxt[li], 1);
    ecl[pos] = e / 3;
}

#define BKT 64

// =========== Fused 3-layer MLP (256->256->256->256), relu/relu/linear ===========
// 32 rows per block; activations live in LDS across layers.
#define MLPR 32
__global__ __launch_bounds__(256) void mlp3_kernel(
    const ushort* __restrict__ A,
    const ushort* __restrict__ W0t, const float* __restrict__ b0,
    const ushort* __restrict__ W1t, const float* __restrict__ b1,
    const ushort* __restrict__ W2t, const float* __restrict__ b2,
    ushort* __restrict__ out, int M)
{
    __shared__ __align__(16) ushort As[MLPR * BKT];    // layer0 A k-tile (XOR swizzle)
    __shared__ __align__(16) ushort Wl[256 * BKT];     // W k-tile (XOR swizzle)
    __shared__ __align__(16) ushort Ab[MLPR * 264];    // padded activation buffer
    const int tid = threadIdx.x;
    const int lane = tid & 63, wid = tid >> 6;
    const int rowBase = blockIdx.x * MLPR;
    const int lr = lane >> 3, ql = (lane & 7) ^ lr;
    const int cl16 = lane & 15, kg = lane >> 4;

    const ushort* Wt[3] = {W0t, W1t, W2t};
    const float*  bs[3] = {b0, b1, b2};

    #pragma unroll
    for (int layer = 0; layer < 3; ++layer) {
        f32x4 acc[2][4];
        #pragma unroll
        for (int i = 0; i < 2; ++i)
            #pragma unroll
            for (int j = 0; j < 4; ++j) acc[i][j] = (f32x4){0.f, 0.f, 0.f, 0.f};

        for (int kt = 0; kt < 4; ++kt) {
            __syncthreads();
            // stage W: wave wid stages rows [wid*64, wid*64+64)
            #pragma unroll
            for (int t = 0; t < 8; ++t) {
                int row = wid * 64 + t * 8 + lr;
                __builtin_amdgcn_global_load_lds(
                    (gaddr_t)(Wt[layer] + (size_t)row * 256 + kt * 64 + ql * 8),
                    (laddr_t)&Wl[(wid * 64 + t * 8) * BKT + lane * 8], 16, 0, 0);
            }
            if (layer == 0) {
                int row = rowBase + wid * 8 + lr;
                if (row > M - 1) row = M - 1;
                __builtin_amdgcn_global_load_lds(
                    (gaddr_t)(A + (size_t)row * 256 + kt * 64 + ql * 8),
                    (laddr_t)&As[wid * 512 + lane * 8], 16, 0, 0);
            }
            __syncthreads();
            #pragma unroll
            for (int s = 0; s < 2; ++s) {
                int kq8 = s * 4 + kg;
                V8 af[2], bf[4];
                #pragma unroll
                for (int i = 0; i < 2; ++i) {
                    int m = i * 16 + cl16;
                    if (layer == 0)
                        af[i].s = *(const s16x8*)&As[m * BKT + ((kq8 ^ (m & 7)) * 8)];
                    else
                        af[i].s = *(const s16x8*)&Ab[m * 264 + kt * 64 + kq8 * 8];
                }
                #pragma unroll
                for (int j = 0; j < 4; ++j) {
                    int n = wid * 64 + j * 16 + cl16;
                    bf[j].s = *(const s16x8*)&Wl[n * BKT + ((kq8 ^ (n & 7)) * 8)];
                }
                #pragma unroll
                for (int i = 0; i < 2; ++i)
                    #pragma unroll
                    for (int j = 0; j < 4; ++j)
                        acc[i][j] = __builtin_amdgcn_mfma_f32_16x16x32_bf16(
                            af[i].b, bf[j].b, acc[i][j], 0, 0, 0);
            }
        }
        // epilogue
        __syncthreads();
        const int rq = (lane >> 4) * 4;
        #pragma unroll
        for (int i = 0; i < 2; ++i)
            #pragma unroll
            for (int r = 0; r < 4; ++r) {
                int row = i * 16 + rq + r;
                #pragma unroll
                for (int j = 0; j < 4; ++j) {
                    int col = wid * 64 + j * 16 + cl16;
                    float v = acc[i][j][r] + bs[layer][col];
                    if (layer < 2) {
                        Ab[row * 264 + col] = f2b(fmaxf(v, 0.0f));
                    } else {
                        int grow = rowBase + row;
                        if (grow < M) out[(size_t)grow * 256 + col] = f2b(v);
                    }
                }
            }
    }
}

// =========== MFMA bf16 GEMM 128x64 tile (vote MLP) ===========
__global__ __launch_bounds__(256) void gemm16_n64_kernel(
    const ushort* __restrict__ A0, int K0,
    const ushort* __restrict__ A1, int K1,
    const ushort* __restrict__ Bt, const float* __restrict__ bias,
    ushort* __restrict__ C, int M, int N, int relu)
{
    __shared__ __align__(16) ushort Al[128 * BKT];
    __shared__ __align__(16) ushort Bl[64 * BKT];
    const int Ktot = K0 + K1;
    const int tid = threadIdx.x;
    const int rowBase = blockIdx.y * 128, colBase = blockIdx.x * 64;
    const int lane = tid & 63, wid = tid >> 6;
    const int wm = (wid & 1) * 64, wn = (wid >> 1) * 32;
    const int lr = lane >> 3, ql = (lane & 7) ^ lr;

    f32x4 acc[4][2];
    #pragma unroll
    for (int i = 0; i < 4; ++i)
        #pragma unroll
        for (int j = 0; j < 2; ++j) acc[i][j] = (f32x4){0.f, 0.f, 0.f, 0.f};

    for (int k0 = 0; k0 < Ktot; k0 += BKT) {
        const ushort* As; int ks, lda;
        if (k0 < K0) { As = A0; ks = k0; lda = K0; }
        else         { As = A1; ks = k0 - K0; lda = K1; }
        __syncthreads();
        #pragma unroll
        for (int t = 0; t < 4; ++t) {
            int rloc = (wid * 4 + t) * 8 + lr;
            int ga = rowBase + rloc; if (ga > M - 1) ga = M - 1;
            __builtin_amdgcn_global_load_lds((gaddr_t)(As + (size_t)ga * lda + ks + ql * 8),
                                             (laddr_t)&Al[(wid * 4 + t) * 512], 16, 0, 0);
        }
        #pragma unroll
        for (int t = 0; t < 2; ++t) {
            int rloc = (wid * 2 + t) * 8 + lr;
            __builtin_amdgcn_global_load_lds((gaddr_t)(Bt + (size_t)(colBase + rloc) * Ktot + k0 + ql * 8),
                                             (laddr_t)&Bl[(wid * 2 + t) * 512], 16, 0, 0);
        }
        __syncthreads();
        const int cl = lane & 15, kg = lane >> 4;
        #pragma unroll
        for (int s = 0; s < 2; ++s) {
            V8 af[4], bf[2];
            #pragma unroll
            for (int i = 0; i < 4; ++i) {
                int m = wm + i * 16 + cl;
                af[i].s = *(const s16x8*)&Al[m * BKT + (((s * 4 + kg) ^ (m & 7)) * 8)];
            }
            #pragma unroll
            for (int j = 0; j < 2; ++j) {
                int n = wn + j * 16 + cl;
                bf[j].s = *(const s16x8*)&Bl[n * BKT + (((s * 4 + kg) ^ (n & 7)) * 8)];
            }
            #pragma unroll
            for (int i = 0; i < 4; ++i)
                #pragma unroll
                for (int j = 0; j < 2; ++j)
                    acc[i][j] = __builtin_amdgcn_mfma_f32_16x16x32_bf16(af[i].b, bf[j].b,
                                                                        acc[i][j], 0, 0, 0);
        }
    }
    const int rq = (lane >> 4) * 4, cl = lane & 15;
    #pragma unroll
    for (int i = 0; i < 4; ++i)
        #pragma unroll
        for (int r = 0; r < 4; ++r) {
            int grow = rowBase + wm + i * 16 + rq + r;
            if (grow >= M) continue;
            #pragma unroll
            for (int j = 0; j < 2; ++j) {
                int gcol = colBase + wn + j * 16 + cl;
                float v = acc[i][j][r] + bias[gcol];
                if (relu) v = fmaxf(v, 0.0f);
                C[(size_t)grow * N + gcol] = f2b(v);
            }
        }
}

// =========== Fused z-GEMM + LSTM (N=1024, gate-interleaved weights) ===========
__global__ __launch_bounds__(256) void gemm_lstm_kernel(
    const ushort* __restrict__ A0, int K0,
    const ushort* __restrict__ A1, int K1,
    const ushort* __restrict__ A2, int K2,
    const ushort* __restrict__ Bt, const float* __restrict__ biasP,
    float* __restrict__ c32, ushort* __restrict__ h_out,
    ushort* __restrict__ hflip_out, int M)
{
    __shared__ __align__(16) ushort smem[2 * 128 * BKT];   // staging; reused as zt[128][128]
    ushort* Al = smem;
    ushort* Bl = smem + 128 * BKT;
    const int Ktot = K0 + K1 + K2;
    const int tid = threadIdx.x;
    const int rowBase = blockIdx.y * 128, colBase = blockIdx.x * 128;
    const int lane = tid & 63, wid = tid >> 6;
    const int wm = (wid >> 1) * 64, wn = (wid & 1) * 64;
    const int lr = lane >> 3, ql = (lane & 7) ^ lr;

    f32x4 acc[4][4];
    #pragma unroll
    for (int i = 0; i < 4; ++i)
        #pragma unroll
        for (int j = 0; j < 4; ++j) acc[i][j] = (f32x4){0.f, 0.f, 0.f, 0.f};

    for (int k0 = 0; k0 < Ktot; k0 += BKT) {
        const ushort* As; int ks, lda;
        if (k0 < K0)           { As = A0; ks = k0;           lda = K0; }
        else if (k0 < K0 + K1) { As = A1; ks = k0 - K0;      lda = K1; }
        else                   { As = A2; ks = k0 - K0 - K1; lda = K2; }
        __syncthreads();
        #pragma unroll
        for (int t = 0; t < 4; ++t) {
            int rloc = (wid * 4 + t) * 8 + lr;
            int ga = rowBase + rloc; if (ga > M - 1) ga = M - 1;
            __builtin_amdgcn_global_load_lds((gaddr_t)(As + (size_t)ga * lda + ks + ql * 8),
                                             (laddr_t)&Al[(wid * 4 + t) * 512], 16, 0, 0);
            __builtin_amdgcn_global_load_lds((gaddr_t)(Bt + (size_t)(colBase + rloc) * Ktot + k0 + ql * 8),
                                             (laddr_t)&Bl[(wid * 4 + t) * 512], 16, 0, 0);
        }
        __syncthreads();
        const int cl = lane & 15, kg = lane >> 4;
        #pragma unroll
        for (int s = 0; s < 2; ++s) {
            V8 af[4], bf[4];
            #pragma unroll
            for (int i = 0; i < 4; ++i) {
                int m = wm + i * 16 + cl;
                af[i].s = *(const s16x8*)&Al[m * BKT + (((s * 4 + kg) ^ (m & 7)) * 8)];
            }
            #pragma unroll
            for (int j = 0; j < 4; ++j) {
                int n = wn + j * 16 + cl;
                bf[j].s = *(const s16x8*)&Bl[n * BKT + (((s * 4 + kg) ^ (n & 7)) * 8)];
            }
            #pragma unroll
            for (int i = 0; i < 4; ++i)
                #pragma unroll
                for (int j = 0; j < 4; ++j)
                    acc[i][j] = __builtin_amdgcn_mfma_f32_16x16x32_bf16(af[i].b, bf[j].b,
                                                                        acc[i][j], 0, 0, 0);
        }
    }
    // ---- epilogue: z tile (bf16, post-bias) into LDS ----
    __syncthreads();
    {
        const int rq = (lane >> 4) * 4, cl = lane & 15;
        #pragma unroll
        for (int i = 0; i < 4; ++i)
            #pragma unroll
            for (int r = 0; r < 4; ++r) {
                int rl = wm + i * 16 + rq + r;
                #pragma unroll
                for (int j = 0; j < 4; ++j) {
                    int clc = wn + j * 16 + cl;
                    smem[rl * 128 + clc] = f2b(acc[i][j][r] + biasP[colBase + clc]);
                }
            }
    }
    __syncthreads();
    // ---- LSTM: 32 features x 128 rows per block ----
    const int fl = tid & 31, rg = tid >> 5;
    const int fglob = (colBase >> 2) + fl;
    #pragma unroll
    for (int k = 0; k < 16; ++k) {
        int rl = rg + 8 * k;
        int grow = rowBase + rl;
        if (grow >= M) continue;
        ushort4 g4 = *(const ushort4*)&smem[rl * 128 + fl * 4];
        float zi = b2f(g4.x), zf = b2f(g4.y), zg = b2f(g4.z), zo = b2f(g4.w);
        size_t ci = (size_t)grow * FM + fglob;
        float cold = c32[ci];
        float si = 1.0f / (1.0f + __expf(-zi));
        float sf = 1.0f / (1.0f + __expf(-zf));
        float so = 1.0f / (1.0f + __expf(-zo));
        float cn = sf * cold + si * tanhf(zg);
        float hn = so * tanhf(cn);
        c32[ci] = cn;
        ushort hb = f2b(hn);
        h_out[ci] = hb;
        if (hflip_out) hflip_out[(size_t)((grow + NV) % NL) * FM + fglob] = hb;
    }
}

// ---------------- gather (vectorized x8): lcm[c] = sum_k lc_pre[lit(c,k)] -----------
__global__ void gather_lc8_kernel(const ushort* __restrict__ pre, const int* __restrict__ lits,
                                  ushort* __restrict__ out) {
    int idx = blockIdx.x * blockDim.x + threadIdx.x;
    if (idx >= NC * 32) return;
    int c = idx >> 5, f8 = (idx & 31) * 8;
    const int* cl = lits + c * 3;
    float s[8] = {};
    #pragma unroll
    for (int k = 0; k < 3; ++k) {
        int l = cl[k];
        int v = (l > 0 ? l : -l) - 1;
        int li = (l > 0) ? v : NV + v;
        V8 x; x.s = *(const s16x8*)&pre[(size_t)li * FM + f8];
        #pragma unroll
        for (int e = 0; e < 8; ++e) s[e] += b2f(x.u[e]);
    }
    V8 o;
    #pragma unroll
    for (int e = 0; e < 8; ++e) o.u[e] = f2b(s[e]);
    *(s16x8*)&out[(size_t)c * FM + f8] = o.s;
}

// ---------------- CSR gather (vectorized x8) ----------------------------------------
__global__ void gather_cl8_kernel(const ushort* __restrict__ pre, const int* __restrict__ rowptr,
                                  const int* __restrict__ ecl, ushort* __restrict__ out) {
    int idx = blockIdx.x * blockDim.x + threadIdx.x;
    if (idx >= NL * 32) return;
    int li = idx >> 5, f8 = (idx & 31) * 8;
    int j0 = rowptr[li], j1 = rowptr[li + 1];
    float s[8] = {};
    for (int j = j0; j < j1; ++j) {
        V8 x; x.s = *(const s16x8*)&pre[(size_t)ecl[j] * FM + f8];
        #pragma unroll
        for (int e = 0; e < 8; ++e) s[e] += b2f(x.u[e]);
    }
    V8 o;
    #pragma unroll
    for (int e = 0; e < 8; ++e) o.u[e] = f2b(s[e]);
    *(s16x8*)&out[(size_t)li * FM + f8] = o.s;
}

// ---------------- vote output GEMV: logits -> hist slot + d_out ----------------
__global__ void vote_out_kernel(const ushort* __restrict__ h1, const ushort* __restrict__ w,
                                const float* __restrict__ b, float* __restrict__ logits_hist,
                                float* __restrict__ out_f32) {
    int gtid = blockIdx.x * blockDim.x + threadIdx.x;
    int wid = gtid >> 6;
    int lane = threadIdx.x & 63;
    if (wid >= NV) return;
    const ushort* hr = h1 + (size_t)wid * 512;
    float s = 0.0f;
    #pragma unroll
    for (int k = 0; k < 8; ++k) s += b2f(hr[lane + 64 * k]) * b2f(w[lane + 64 * k]);
    #pragma unroll
    for (int off = 32; off; off >>= 1) s += __shfl_down(s, off);
    if (lane == 0) {
        float v = s + b[0];
        logits_hist[wid] = v;
        out_f32[wid] = v;
    }
}

// ---------------- batched clause loss over all rounds ----------------
__global__ __launch_bounds__(256) void loss_all_kernel(
    const float* __restrict__ logits_hist, const int* __restrict__ lits,
    float* __restrict__ loss_arr)
{
    __shared__ float sm[256];
    const int r = blockIdx.y;
    const float* logits = logits_hist + (size_t)r * NV;
    int c = blockIdx.x * 256 + threadIdx.x;
    float t2 = 0.0f;
    if (c < NC) {
        const int* cl = lits + c * 3;
        float s = 0.0f;
        #pragma unroll
        for (int k = 0; k < 3; ++k) {
            int l = cl[k];
            int v = (l > 0 ? l : -l) - 1;
            float sg = (l > 0) ? 1.0f : -1.0f;
            float val = logits[v] * sg;
            s += fmaxf(val, 0.0f) + log1pf(__expf(-fabsf(val)));
        }
        float cv = __expf(-s);
        float t = -logf(1.0f - cv + 1e-8f);
        t2 = t * t;
    }
    sm[threadIdx.x] = t2;
    __syncthreads();
    for (int st = 128; st > 0; st >>= 1) {
        if (threadIdx.x < st) sm[threadIdx.x] += sm[threadIdx.x + st];
        __syncthreads();
    }
    if (threadIdx.x == 0) atomicAdd(&loss_arr[r], sm[0]);
}

__global__ void final_loss_kernel(const float* __restrict__ loss_arr, float* __restrict__ out) {
    if (threadIdx.x == 0 && blockIdx.x == 0) {
        float s = 0.0f;
        for (int r = 0; r < ROUNDS; ++r) s += loss_arr[r];
        out[NV] = s * (1.0f / (float)ROUNDS);
    }
}

extern "C" void kernel_launch(void* const* d_in, const int* in_sizes, int n_in,
                              void* d_out, int out_size, void* d_ws, size_t ws_size,
                              hipStream_t stream) {
    const int* lits = (const int*)d_in[0];
    float* out = (float*)d_out;

    const float* Li   = (const float*)d_in[2];
    const float* Ci   = (const float*)d_in[3];
    const float* LCW0 = (const float*)d_in[4];
    const float* LCb0 = (const float*)d_in[5];
    const float* LCW1 = (const float*)d_in[6];
    const float* LCb1 = (const float*)d_in[7];
    const float* LCW2 = (const float*)d_in[8];
    const float* LCb2 = (const float*)d_in[9];
    const float* CLW0 = (const float*)d_in[10];
    const float* CLb0 = (const float*)d_in[11];
    const float* CLW1 = (const float*)d_in[12];
    const float* CLb1 = (const float*)d_in[13];
    const float* CLW2 = (const float*)d_in[14];
    const float* CLb2 = (const float*)d_in[15];
    const float* CWx  = (const float*)d_in[16];
    const float* CWh  = (const float*)d_in[17];
    const float* Cb   = (const float*)d_in[18];
    const float* LWx  = (const float*)d_in[19];
    const float* LWh  = (const float*)d_in[20];
    const float* Lb   = (const float*)d_in[21];
    const float* VW0  = (const float*)d_in[22];
    const float* Vb0  = (const float*)d_in[23];
    const float* VW1  = (const float*)d_in[24];
    const float* Vb1  = (const float*)d_in[25];
    const float* VW2  = (const float*)d_in[26];
    const float* Vb2  = (const float*)d_in[27];
    (void)in_sizes; (void)n_in; (void)out_size; (void)ws_size;

    // ---- ws layout ----
    char* base = (char*)d_ws;
    size_t off = 0;
    auto allocB = [&](size_t bytes) {
        void* p = base + off;
        off += (bytes + 15) & ~(size_t)15;
        return p;
    };
    float*  loss_arr    = (float*)allocB(ROUNDS * 4);
    float*  logits_hist = (float*)allocB((size_t)ROUNDS * NV * 4);
    float*  lc32        = (float*)allocB((size_t)NL * FM * 4);
    float*  cc32        = (float*)allocB((size_t)NC * FM * 4);
    float*  Cb_p        = (float*)allocB(1024 * 4);
    float*  Lb_p        = (float*)allocB(1024 * 4);
    int*    deg         = (int*)allocB(NL * 4);
    int*    rowptr      = (int*)allocB((NL + 1) * 4);
    int*    nxt         = (int*)allocB(NL * 4);
    int*    ecl         = (int*)allocB(NE * 4);
    ushort* LC0t = (ushort*)allocB((size_t)256 * 256 * 2);
    ushort* LC1t = (ushort*)allocB((size_t)256 * 256 * 2);
    ushort* LC2t = (ushort*)allocB((size_t)256 * 256 * 2);
    ushort* CL0t = (ushort*)allocB((size_t)256 * 256 * 2);
    ushort* CL1t = (ushort*)allocB((size_t)256 * 256 * 2);
    ushort* CL2t = (ushort*)allocB((size_t)256 * 256 * 2);
    ushort* CWt  = (ushort*)allocB((size_t)1024 * 512 * 2);
    ushort* LWt  = (ushort*)allocB((size_t)1024 * 768 * 2);
    ushort* VW0t = (ushort*)allocB((size_t)512 * 512 * 2);
    ushort* VW1t = (ushort*)allocB((size_t)512 * 512 * 2);
    ushort* vw2  = (ushort*)allocB((size_t)512 * 2);
    ushort* lh_a = (ushort*)allocB((size_t)NL * FM * 2);
    ushort* lh_b = (ushort*)allocB((size_t)NL * FM * 2);
    ushort* lf_a = (ushort*)allocB((size_t)NL * FM * 2);
    ushort* lf_b = (ushort*)allocB((size_t)NL * FM * 2);
    ushort* ch_a = (ushort*)allocB((size_t)NC * FM * 2);
    ushort* ch_b = (ushort*)allocB((size_t)NC * FM * 2);
    ushort* lcm16 = (ushort*)allocB((size_t)NC * FM * 2);
    ushort* clm16 = (ushort*)allocB((size_t)NL * FM * 2);
    ushort* tL    = (ushort*)allocB((size_t)NL * FM * 2);
    ushort* tC    = (ushort*)allocB((size_t)NC * FM * 2);
    ushort* v0    = (ushort*)allocB((size_t)NV * 512 * 2);
    ushort* v1    = (ushort*)allocB((size_t)NV * 512 * 2);

    // ---- setup: weights, bias permutes, states, CSR ----
    auto tw = [&](const float* in, ushort* o, int K, int N, int ldo, int koff, int perm) {
        hipLaunchKernelGGL(transpose_w_kernel, dim3((K * N + 255) / 256), dim3(256), 0, stream,
                           in, o, K, N, ldo, koff, perm);
    };
    tw(LCW0, LC0t, 256, 256, 256, 0, 0);
    tw(LCW1, LC1t, 256, 256, 256, 0, 0);
    tw(LCW2, LC2t, 256, 256, 256, 0, 0);
    tw(CLW0, CL0t, 256, 256, 256, 0, 0);
    tw(CLW1, CL1t, 256, 256, 256, 0, 0);
    tw(CLW2, CL2t, 256, 256, 256, 0, 0);
    tw(CWx,  CWt, 256, 1024, 512, 0, 1);
    tw(CWh,  CWt, 256, 1024, 512, 256, 1);
    tw(LWx,  LWt, 512, 1024, 768, 0, 1);
    tw(LWh,  LWt, 256, 1024, 768, 512, 1);
    tw(VW0,  VW0t, 512, 512, 512, 0, 0);
    tw(VW1,  VW1t, 512, 512, 512, 0, 0);
    hipLaunchKernelGGL(f2b_kernel, dim3(2), dim3(256), 0, stream, VW2, vw2, 512);
    hipLaunchKernelGGL(permute_bias_kernel, dim3(4), dim3(256), 0, stream, Cb, Cb_p);
    hipLaunchKernelGGL(permute_bias_kernel, dim3(4), dim3(256), 0, stream, Lb, Lb_p);

    hipLaunchKernelGGL(init_lh_kernel, dim3(NL * FM / 256), dim3(256), 0, stream, Li, lh_a, lf_a);
    hipLaunchKernelGGL(init_ch_kernel, dim3(NC * FM / 256), dim3(256), 0, stream, Ci, ch_a);
    hipLaunchKernelGGL(zero_kernel, dim3(NL * FM / 256), dim3(256), 0, stream, lc32, NL * FM);
    hipLaunchKernelGGL(zero_kernel, dim3(NC * FM / 256), dim3(256), 0, stream, cc32, NC * FM);
    hipLaunchKernelGGL(zero_kernel, dim3(1), dim3(256), 0, stream, loss_arr, ROUNDS);
    hipLaunchKernelGGL(zero_kernel, dim3((NL + 255) / 256), dim3(256), 0, stream, (float*)deg, NL);
    hipLaunchKernelGGL(csr_count_kernel, dim3((NE + 255) / 256), dim3(256), 0, stream, lits, deg);
    hipLaunchKernelGGL(csr_scan_kernel, dim3(1), dim3(64), 0, stream, deg, rowptr, nxt);
    hipLaunchKernelGGL(csr_fill_kernel, dim3((NE + 255) / 256), dim3(256), 0, stream, lits, nxt, ecl);

    auto gemm64 = [&](const ushort* A0, int K0, const ushort* A1, int K1,
                      const ushort* Bt, const float* bias, ushort* C, int M, int N, int relu) {
        hipLaunchKernelGGL(gemm16_n64_kernel, dim3(N / 64, (M + 127) / 128), dim3(256), 0, stream,
                           A0, K0, A1, K1, Bt, bias, C, M, N, relu);
    };

    ushort *lh_c = lh_a, *lh_n = lh_b, *lf_c = lf_a, *lf_n = lf_b, *ch_c = ch_a, *ch_n = ch_b;

    for (int r = 0; r < ROUNDS; ++r) {
        // L -> C message MLP (fused 3 layers)
        hipLaunchKernelGGL(mlp3_kernel, dim3(NL / MLPR), dim3(256), 0, stream,
                           lh_c, LC0t, LCb0, LC1t, LCb1, LC2t, LCb2, tL, NL);
        // gather into clauses
        hipLaunchKernelGGL(gather_lc8_kernel, dim3(NC * 32 / 256), dim3(256), 0, stream,
                           tL, lits, lcm16);
        // fused clause z-GEMM + LSTM
        hipLaunchKernelGGL(gemm_lstm_kernel, dim3(8, (NC + 127) / 128), dim3(256), 0, stream,
                           lcm16, 256, ch_c, 256, (const ushort*)0, 0,
                           CWt, Cb_p, cc32, ch_n, (ushort*)0, NC);
        // C -> L message MLP (fused 3 layers)
        hipLaunchKernelGGL(mlp3_kernel, dim3(NC / MLPR, 1), dim3(256), 0, stream,
                           ch_n, CL0t, CLb0, CL1t, CLb1, CL2t, CLb2, tC, NC);
        // CSR gather into literals
        hipLaunchKernelGGL(gather_cl8_kernel, dim3(NL * 32 / 256), dim3(256), 0, stream,
                           tC, rowptr, ecl, clm16);
        // fused literal z-GEMM + LSTM
        hipLaunchKernelGGL(gemm_lstm_kernel, dim3(8, (NL + 127) / 128), dim3(256), 0, stream,
                           clm16, 256, lf_c, 256, lh_c, 256,
                           LWt, Lb_p, lc32, lh_n, lf_n, NL);
        // vote MLP
        gemm64(lh_n, 256, lh_n + (size_t)NV * FM, 256, VW0t, Vb0, v0, NV, 512, 1);
        gemm64(v0, 512, 0, 0, VW1t, Vb1, v1, NV, 512, 1);
        hipLaunchKernelGGL(vote_out_kernel, dim3(NV * 64 / 256), dim3(256), 0, stream,
                           v1, vw2, Vb2, logits_hist + (size_t)r * NV, out);
        // swap state buffers
        ushort* tswap;
        tswap = lh_c; lh_c = lh_n; lh_n = tswap;
        tswap = lf_c; lf_c = lf_n; lf_n = tswap;
        tswap = ch_c; ch_c = ch_n; ch_n = tswap;
    }

    // batched loss over all rounds, then final reduce
    hipLaunchKernelGGL(loss_all_kernel, dim3((NC + 255) / 256, ROUNDS), dim3(256), 0, stream,
                       logits_hist, lits, loss_arr);
    hipLaunchKernelGGL(final_loss_kernel, dim3(1), dim3(64), 0, stream, loss_arr, out);
}